// Round 12
// baseline (924.855 us; speedup 1.0000x reference)
//
#include <hip/hip_runtime.h>
#include <hip/hip_bf16.h>
#include <math.h>

// Problem constants
#define HH 128
#define WWW 128
#define BB 8
#define MM (HH*WWW*BB)      // 131072 rows (h,w,b)

typedef unsigned int u32;
typedef unsigned short u16;

__device__ __forceinline__ float b2f(u16 s){ return __uint_as_float(((u32)s)<<16); }
__device__ __forceinline__ u16 f2b(float f){
    u32 u = __float_as_uint(f);
    return (u16)((u + 0x7fffu + ((u>>16)&1u)) >> 16);
}
__device__ __forceinline__ u32 pack2(float lo, float hi){
    return (u32)f2b(lo) | ((u32)f2b(hi)<<16);
}

// ---------------- K0: trig tables + W_out -> bf16 cast -----------------------
__global__ __launch_bounds__(128) void k_prep(const float* __restrict__ th_f,
                                              const float* __restrict__ th_r,
                                              const float* __restrict__ W_out,
                                              float* __restrict__ trig,
                                              u16* __restrict__ WoB)
{
    int t = blockIdx.x*128 + threadIdx.x;     // 257 blocks x 128
    if (t < 32768) {
        WoB[t] = f2b(W_out[t]);               // natural order [k][n]
    } else if (t < 32896) {
        int d = t - 32768;
        trig[d]     = cosf(th_f[d]); trig[128+d] = sinf(th_f[d]);
        trig[256+d] = cosf(th_r[d]); trig[384+d] = sinf(th_r[d]);
    }
}

// ---------------- K1: front GEMM v3 — x f32 LDS, W bf16-packed LDS ----------
// Grid 5120 = 1024 m-tiles (outer) x 5 n-tiles (inner). n-tile->dest:
//   nt 0,1 -> SC (silu);  nt 2 -> OM (1-sigmoid);  nt 3,4 -> GATE (silu)
// LDS: xs[32][132] f32 (16.9 KB) + wp[32][68] u32 bf16-pairs (8.7 KB) = 25.6 KB
#define LDT 132
__global__ __launch_bounds__(256, 4) void k_front2(
    const float* __restrict__ x,
    const float* __restrict__ W_in,   const float* __restrict__ b_in,
    const float* __restrict__ W_lam,  const float* __restrict__ b_lam,
    const float* __restrict__ W_gate, const float* __restrict__ b_gate,
    u16* __restrict__ SC, u16* __restrict__ OM, u16* __restrict__ GATE)
{
    __shared__ float xs[32][LDT];   // [k][row]
    __shared__ u32 wp[32][68];      // [k][col-pair], bf16x2
    int tid = threadIdx.x;
    int bid = blockIdx.x;
    int mt = bid / 5, nt = bid % 5;
    int m0 = mt * 128;

    const float* Wsrc; int ldw, nw0; const float* bsrc;
    if (nt < 2)       { Wsrc = W_in;   ldw = 256; nw0 = nt*128;     bsrc = b_in + nt*128; }
    else if (nt == 2) { Wsrc = W_lam;  ldw = 128; nw0 = 0;          bsrc = b_lam; }
    else              { Wsrc = W_gate; ldw = 256; nw0 = (nt-3)*128; bsrc = b_gate + (nt-3)*128; }

    int ri = tid >> 4, ci = tid & 15;

    float bias[8];
    #pragma unroll
    for (int t = 0; t < 2; ++t)
    #pragma unroll
    for (int j = 0; j < 4; ++j)
        bias[t*4+j] = bsrc[t*64 + ci*4 + j];

    float acc[8][8] = {};

    for (int kc = 0; kc < 4; ++kc) {
        int k0 = kc * 32;
        __syncthreads();                 // protect prev-chunk LDS reads
        #pragma unroll
        for (int it = 0; it < 4; ++it) { // stage x: 128 rows x 32 k (f32)
            int u = it*256 + tid;
            int row = u >> 3, kq = u & 7;
            float4 v = *(const float4*)(x + (size_t)(m0+row)*128 + k0 + kq*4);
            xs[kq*4+0][row] = v.x; xs[kq*4+1][row] = v.y;
            xs[kq*4+2][row] = v.z; xs[kq*4+3][row] = v.w;
        }
        #pragma unroll
        for (int it = 0; it < 8; ++it) { // stage W: 32 k x 128 cols -> bf16 pairs
            int u = it*256 + tid;        // 2048 u32 units
            int krow = u >> 6, c2 = u & 63;
            const float* wsp = Wsrc + (size_t)(k0+krow)*ldw + nw0 + c2*2;
            wp[krow][c2] = pack2(wsp[0], wsp[1]);
        }
        __syncthreads();

        #pragma unroll 4
        for (int k = 0; k < 32; ++k) {
            float4 a0 = *(const float4*)(&xs[k][ri*4]);
            float4 a1 = *(const float4*)(&xs[k][64 + ri*4]);
            uint2 p0 = *(const uint2*)(&wp[k][ci*2]);
            uint2 p1 = *(const uint2*)(&wp[k][32 + ci*2]);
            float w0 = b2f((u16)(p0.x & 0xffff)), w1 = b2f((u16)(p0.x >> 16));
            float w2 = b2f((u16)(p0.y & 0xffff)), w3 = b2f((u16)(p0.y >> 16));
            float w4 = b2f((u16)(p1.x & 0xffff)), w5 = b2f((u16)(p1.x >> 16));
            float w6 = b2f((u16)(p1.y & 0xffff)), w7 = b2f((u16)(p1.y >> 16));
            #define FMA_ROW(r, av)                               \
                acc[r][0] = fmaf(av, w0, acc[r][0]);             \
                acc[r][1] = fmaf(av, w1, acc[r][1]);             \
                acc[r][2] = fmaf(av, w2, acc[r][2]);             \
                acc[r][3] = fmaf(av, w3, acc[r][3]);             \
                acc[r][4] = fmaf(av, w4, acc[r][4]);             \
                acc[r][5] = fmaf(av, w5, acc[r][5]);             \
                acc[r][6] = fmaf(av, w6, acc[r][6]);             \
                acc[r][7] = fmaf(av, w7, acc[r][7]);
            FMA_ROW(0, a0.x) FMA_ROW(1, a0.y) FMA_ROW(2, a0.z) FMA_ROW(3, a0.w)
            FMA_ROW(4, a1.x) FMA_ROW(5, a1.y) FMA_ROW(6, a1.z) FMA_ROW(7, a1.w)
            #undef FMA_ROW
        }
    }

    // epilogue: activation + bf16 pack + store (8 rows x 2 col-groups of 4)
    #pragma unroll
    for (int rr = 0; rr < 8; ++rr) {
        int m = m0 + ((rr < 4) ? (ri*4 + rr) : (64 + ri*4 + rr - 4));
        #pragma unroll
        for (int t = 0; t < 2; ++t) {
            float v[4];
            #pragma unroll
            for (int j = 0; j < 4; ++j) {
                float tv = acc[rr][t*4+j] + bias[t*4+j];
                float e = __expf(-tv);
                v[j] = (nt == 2) ? e/(1.f+e) : tv/(1.f+e);
            }
            uint2 pk = make_uint2(pack2(v[0], v[1]), pack2(v[2], v[3]));
            int cl = t*64 + ci*4;
            if (nt < 2)
                *(uint2*)(&SC[(size_t)m*256 + nt*128 + cl]) = pk;
            else if (nt == 2)
                *(uint2*)(&OM[(size_t)m*128 + cl]) = pk;
            else
                *(uint2*)(&GATE[(size_t)m*256 + (nt-3)*128 + cl]) = pk;
        }
    }
}

// ---------------- K2: fused fwd+rev complex scans, full-d, bf16 I/O ----------
template<int AXISW, int FIRSTPAIR>
__global__ __launch_bounds__(256) void k_scan2(const u16* __restrict__ SC,
                                               const u16* __restrict__ OM,
                                               const float* __restrict__ trig,
                                               u32* P)
{
    int j = blockIdx.x*256 + threadIdx.x;  // 131072 columns (full d)
    int d = j & 127;
    int col = j >> 7;                      // 0..1023
    int rowbase, stride;
    if (AXISW) { rowbase = (col>>3)*1024 + (col&7); stride = 8; }
    else       { rowbase = col;                     stride = 1024; }

    float cfF = trig[d],     sfF = trig[128+d];
    float cfR = trig[256+d], sfR = trig[384+d];

    long long rowF = rowbase;
    long long rowR = (long long)rowbase + (long long)stride*127;

    float hfr=0.f, hfi=0.f, hrr=0.f, hri=0.f;

    #define SCAN_STEP                                                     \
        u32 uF = *(const u32*)(SC + rowF*256 + 2*d);                      \
        float omF = b2f(OM[rowF*128 + d]);                                \
        u32 uR = *(const u32*)(SC + rowR*256 + 2*d);                      \
        float omR = b2f(OM[rowR*128 + d]);                                \
        float lamF = 1.f - omF, lamR = 1.f - omR;                         \
        float grF = lamF*cfF, giF = lamF*sfF;                             \
        float grR = lamR*cfR, giR = lamR*sfR;                             \
        float ieF = b2f((u16)(uF & 0xffff)), ioF = b2f((u16)(uF >> 16));  \
        float ieR = b2f((u16)(uR & 0xffff)), ioR = b2f((u16)(uR >> 16));  \
        float nfr = fmaf(grF, hfr, fmaf(-giF, hfi, omF*ieF));             \
        float nfi = fmaf(grF, hfi, fmaf( giF, hfr, omF*ioF));             \
        hfr = nfr; hfi = nfi;                                             \
        float nrr = fmaf(grR, hrr, fmaf(-giR, hri, omR*ieR));             \
        float nri = fmaf(grR, hri, fmaf( giR, hrr, omR*ioR));             \
        hrr = nrr; hri = nri;                                             \
        long long piF = rowF*128 + d;                                     \
        long long piR = rowR*128 + d;

    if (FIRSTPAIR) {
        #pragma unroll 4
        for (int t = 0; t < 64; ++t, rowF += stride, rowR -= stride) {
            SCAN_STEP
            P[piF] = pack2(hfr, hfi);
            P[piR] = pack2(hrr, hri);
        }
        #pragma unroll 4
        for (int t = 64; t < 128; ++t, rowF += stride, rowR -= stride) {
            SCAN_STEP
            u32 oF = P[piF];
            P[piF] = pack2(b2f((u16)(oF&0xffff)) + hfr, b2f((u16)(oF>>16)) + hfi);
            u32 oR = P[piR];
            P[piR] = pack2(b2f((u16)(oR&0xffff)) + hrr, b2f((u16)(oR>>16)) + hri);
        }
    } else {
        #pragma unroll 4
        for (int t = 0; t < 128; ++t, rowF += stride, rowR -= stride) {
            SCAN_STEP
            u32 oF = P[piF];
            P[piF] = pack2(b2f((u16)(oF&0xffff)) + hfr, b2f((u16)(oF>>16)) + hfi);
            u32 oR = P[piR];
            P[piR] = pack2(b2f((u16)(oR&0xffff)) + hrr, b2f((u16)(oR>>16)) + hri);
        }
    }
    #undef SCAN_STEP
}

// ---------------- K3: LN + gate + out GEMM; bf16 fgT + bf16 W, 4x8 tiles ----
#define GETC(v,i) ((i)==0?(v).x:(i)==1?(v).y:(i)==2?(v).z:(v).w)
__global__ __launch_bounds__(256, 4) void k_backend_f32(
    const uint4* __restrict__ P4, const u16* __restrict__ GATE,
    const u16* __restrict__ WoB, const float* __restrict__ ln_w,
    const float* __restrict__ ln_b, const float* __restrict__ bo,
    float* __restrict__ out)
{
    __shared__ u16 fgT[256][68];                // 34 KiB bf16, [channel][row]
    int tid = threadIdx.x;
    int m0 = blockIdx.x * 64;                   // 2048 blocks
    int r = tid >> 2, q = tid & 3;              // 4 threads per row
    size_t prow4 = (size_t)(m0 + r)*32 + q*8;   // uint4 units (128 u32/row)
    size_t grow = (size_t)(m0 + r)*256;         // u16 units (GATE in ws)

    uint4 ga[4], gb[4];
    #pragma unroll
    for (int g4 = 0; g4 < 4; ++g4) {
        ga[g4] = *(const uint4*)(GATE + grow + q*32 + g4*8);
        gb[g4] = *(const uint4*)(GATE + grow + 128 + q*32 + g4*8);
    }

    uint4 pw[8];                                // 32 packed complex (bf16)
    #pragma unroll
    for (int c4 = 0; c4 < 8; ++c4) pw[c4] = P4[prow4 + c4];

    float fr_[32], fi_[32];
    #pragma unroll
    for (int c4 = 0; c4 < 8; ++c4) {
        #pragma unroll
        for (int w = 0; w < 4; ++w) {
            u32 word = GETC(pw[c4], w);
            int jj = c4*4 + w;
            fr_[jj] = b2f((u16)(word & 0xffff));
            fi_[jj] = b2f((u16)(word >> 16));
        }
    }

    float sum = 0.f, ss = 0.f;
    #pragma unroll
    for (int jj = 0; jj < 32; ++jj) {
        sum += fr_[jj] + fi_[jj];
        ss  += fr_[jj]*fr_[jj] + fi_[jj]*fi_[jj];
    }
    sum += __shfl_xor(sum, 1); sum += __shfl_xor(sum, 2);
    ss  += __shfl_xor(ss, 1);  ss  += __shfl_xor(ss, 2);
    float mu = sum * (1.f/256.f);
    float var = ss * (1.f/256.f) - mu*mu;
    float rstd = rsqrtf(var + 1e-5f);

    #pragma unroll
    for (int jj = 0; jj < 32; ++jj) {
        int pd = q*32 + jj;                     // complex channel 0..127
        int g4 = jj >> 3, e = jj & 7;
        u32 gur = GETC(ga[g4], e>>1), gui = GETC(gb[g4], e>>1);
        float gvr = b2f((u16)((e&1) ? (gur>>16) : (gur&0xffff)));
        float gvi = b2f((u16)((e&1) ? (gui>>16) : (gui&0xffff)));
        float vr = ((fr_[jj] - mu)*rstd*ln_w[pd]     + ln_b[pd])     * gvr;
        float vi = ((fi_[jj] - mu)*rstd*ln_w[128+pd] + ln_b[128+pd]) * gvi;
        fgT[pd][r]     = f2b(vr);
        fgT[128+pd][r] = f2b(vi);
    }
    __syncthreads();

    // out[64][128] = fgT^T @ WoB : 4m x 8n per thread, single pass
    int ri = tid >> 4, ci = tid & 15;
    float acc[4][8] = {};
    #pragma unroll 8
    for (int k = 0; k < 256; ++k) {
        uint2 xr = *(const uint2*)(&fgT[k][ri*4]);
        float xv0 = b2f((u16)(xr.x & 0xffff));
        float xv1 = b2f((u16)(xr.x >> 16));
        float xv2 = b2f((u16)(xr.y & 0xffff));
        float xv3 = b2f((u16)(xr.y >> 16));
        uint4 wv = *(const uint4*)(WoB + (size_t)k*128 + ci*8);
        float w0 = b2f((u16)(wv.x & 0xffff)), w1 = b2f((u16)(wv.x >> 16));
        float w2 = b2f((u16)(wv.y & 0xffff)), w3 = b2f((u16)(wv.y >> 16));
        float w4 = b2f((u16)(wv.z & 0xffff)), w5 = b2f((u16)(wv.z >> 16));
        float w6 = b2f((u16)(wv.w & 0xffff)), w7 = b2f((u16)(wv.w >> 16));
        #define FMA8(i, xv)                                    \
            acc[i][0] = fmaf(xv, w0, acc[i][0]);               \
            acc[i][1] = fmaf(xv, w1, acc[i][1]);               \
            acc[i][2] = fmaf(xv, w2, acc[i][2]);               \
            acc[i][3] = fmaf(xv, w3, acc[i][3]);               \
            acc[i][4] = fmaf(xv, w4, acc[i][4]);               \
            acc[i][5] = fmaf(xv, w5, acc[i][5]);               \
            acc[i][6] = fmaf(xv, w6, acc[i][6]);               \
            acc[i][7] = fmaf(xv, w7, acc[i][7]);
        FMA8(0, xv0) FMA8(1, xv1) FMA8(2, xv2) FMA8(3, xv3)
        #undef FMA8
    }
    #pragma unroll
    for (int i = 0; i < 4; ++i) {
        int m = m0 + ri*4 + i;
        #pragma unroll
        for (int j = 0; j < 8; ++j) {
            int n = ci*8 + j;
            out[(size_t)m*128 + n] = acc[i][j] + bo[n];
        }
    }
}

// ---------------- launch -----------------------------------------------------
extern "C" void kernel_launch(void* const* d_in, const int* in_sizes, int n_in,
                              void* d_out, int out_size, void* d_ws, size_t ws_size,
                              hipStream_t stream)
{
    const float* x      = (const float*)d_in[0];
    const float* W_in   = (const float*)d_in[1];
    const float* b_in   = (const float*)d_in[2];
    const float* W_lam  = (const float*)d_in[3];
    const float* b_lam  = (const float*)d_in[4];
    const float* th_f   = (const float*)d_in[5];
    const float* th_r   = (const float*)d_in[6];
    const float* W_gate = (const float*)d_in[7];
    const float* b_gate = (const float*)d_in[8];
    const float* W_out  = (const float*)d_in[9];
    const float* b_out  = (const float*)d_in[10];
    const float* ln_w   = (const float*)d_in[11];
    const float* ln_b   = (const float*)d_in[12];

    // ws layout: 167,839,744 B <= 168,008,192 B proven-safe envelope
    char* ws = (char*)d_ws;
    u32* P     = (u32*)(ws);                      //  67,108,864 (bf16-pair, full d)
    u16* OM    = (u16*)(ws + 67108864LL);         //  33,554,432 (bf16 om, full d)
    u16* GATE  = (u16*)(ws + 100663296LL);        //  67,108,864 (bf16 gate)
    float* trig= (float*)(ws + 167772160LL);      //   2,048
    u16* WoB   = (u16*)(ws + 167774208LL);        //  65,536 (bf16 W_out)

    // d_out time-shares: SC bf16[M][256] (front->scans) -> out f32[M][128]
    u16* SC   = (u16*)d_out;
    float* out = (float*)d_out;

    hipLaunchKernelGGL(k_prep, dim3(257), dim3(128), 0, stream,
                       th_f, th_r, W_out, trig, WoB);

    hipLaunchKernelGGL(k_front2, dim3(5120), dim3(256), 0, stream,
                       x, W_in, b_in, W_lam, b_lam, W_gate, b_gate,
                       SC, OM, GATE);

    hipLaunchKernelGGL(HIP_KERNEL_NAME(k_scan2<0,1>), dim3(512), dim3(256), 0, stream,
                       SC, OM, trig, P);
    hipLaunchKernelGGL(HIP_KERNEL_NAME(k_scan2<1,0>), dim3(512), dim3(256), 0, stream,
                       SC, OM, trig, P);

    hipLaunchKernelGGL(k_backend_f32, dim3(2048), dim3(256), 0, stream,
                       (const uint4*)P, GATE, WoB, ln_w, ln_b, b_out, out);
}

// Round 13
// 599.873 us; speedup vs baseline: 1.5418x; 1.5418x over previous
//
#include <hip/hip_runtime.h>
#include <hip/hip_bf16.h>
#include <math.h>

// Problem constants
#define HH 128
#define WWW 128
#define BB 8
#define MM (HH*WWW*BB)      // 131072 rows (h,w,b)

typedef unsigned int u32;
typedef unsigned short u16;

__device__ __forceinline__ float b2f(u16 s){ return __uint_as_float(((u32)s)<<16); }
__device__ __forceinline__ u16 f2b(float f){
    u32 u = __float_as_uint(f);
    return (u16)((u + 0x7fffu + ((u>>16)&1u)) >> 16);
}
__device__ __forceinline__ u32 pack2(float lo, float hi){
    return (u32)f2b(lo) | ((u32)f2b(hi)<<16);
}

// ---------------- K0: trig tables + W_out -> bf16 cast -----------------------
__global__ __launch_bounds__(128) void k_prep(const float* __restrict__ th_f,
                                              const float* __restrict__ th_r,
                                              const float* __restrict__ W_out,
                                              float* __restrict__ trig,
                                              u16* __restrict__ WoB)
{
    int t = blockIdx.x*128 + threadIdx.x;     // 257 blocks x 128
    if (t < 32768) {
        WoB[t] = f2b(W_out[t]);               // natural order [k][n]
    } else if (t < 32896) {
        int d = t - 32768;
        trig[d]     = cosf(th_f[d]); trig[128+d] = sinf(th_f[d]);
        trig[256+d] = cosf(th_r[d]); trig[384+d] = sinf(th_r[d]);
    }
}

// ---------------- K1: front GEMM v2 (r11-proven) — 128x128 tile, 8x8/thread -
// Grid 5120 = 1024 m-tiles (outer) x 5 n-tiles (inner). n-tile->dest:
//   nt 0,1 -> SC (silu);  nt 2 -> OM (1-sigmoid);  nt 3,4 -> GATE (silu)
// LDS: xs[32][132] + ws[32][132] f32 (33 KiB) -> 4 blocks/CU.
#define LDT 132
__global__ __launch_bounds__(256, 4) void k_front2(
    const float* __restrict__ x,
    const float* __restrict__ W_in,   const float* __restrict__ b_in,
    const float* __restrict__ W_lam,  const float* __restrict__ b_lam,
    const float* __restrict__ W_gate, const float* __restrict__ b_gate,
    u16* __restrict__ SC, u16* __restrict__ OM, u16* __restrict__ GATE)
{
    __shared__ float xs[32][LDT];   // [k][row]
    __shared__ float ws[32][LDT];   // [k][col]
    int tid = threadIdx.x;
    int bid = blockIdx.x;
    int mt = bid / 5, nt = bid % 5;
    int m0 = mt * 128;

    const float* Wsrc; int ldw, nw0; const float* bsrc;
    if (nt < 2)       { Wsrc = W_in;   ldw = 256; nw0 = nt*128;     bsrc = b_in + nt*128; }
    else if (nt == 2) { Wsrc = W_lam;  ldw = 128; nw0 = 0;          bsrc = b_lam; }
    else              { Wsrc = W_gate; ldw = 256; nw0 = (nt-3)*128; bsrc = b_gate + (nt-3)*128; }

    int ri = tid >> 4, ci = tid & 15;

    float bias[8];
    #pragma unroll
    for (int t = 0; t < 2; ++t)
    #pragma unroll
    for (int j = 0; j < 4; ++j)
        bias[t*4+j] = bsrc[t*64 + ci*4 + j];

    float acc[8][8] = {};

    for (int kc = 0; kc < 4; ++kc) {
        int k0 = kc * 32;
        __syncthreads();                 // protect prev-chunk LDS reads
        #pragma unroll
        for (int it = 0; it < 4; ++it) { // stage x: 128 rows x 32 k
            int u = it*256 + tid;
            int row = u >> 3, kq = u & 7;
            float4 v = *(const float4*)(x + (size_t)(m0+row)*128 + k0 + kq*4);
            xs[kq*4+0][row] = v.x; xs[kq*4+1][row] = v.y;
            xs[kq*4+2][row] = v.z; xs[kq*4+3][row] = v.w;
        }
        #pragma unroll
        for (int it = 0; it < 4; ++it) { // stage W: 32 k x 128 cols
            int u = it*256 + tid;
            int krow = u >> 5, c4 = u & 31;
            float4 v = *(const float4*)(Wsrc + (size_t)(k0+krow)*ldw + nw0 + c4*4);
            *(float4*)(&ws[krow][c4*4]) = v;
        }
        __syncthreads();

        #pragma unroll 4
        for (int k = 0; k < 32; ++k) {
            float4 a0 = *(const float4*)(&xs[k][ri*4]);
            float4 a1 = *(const float4*)(&xs[k][64 + ri*4]);
            float4 b0 = *(const float4*)(&ws[k][ci*4]);
            float4 b1 = *(const float4*)(&ws[k][64 + ci*4]);
            #define FMA_ROW(r, av)                               \
                acc[r][0] = fmaf(av, b0.x, acc[r][0]);           \
                acc[r][1] = fmaf(av, b0.y, acc[r][1]);           \
                acc[r][2] = fmaf(av, b0.z, acc[r][2]);           \
                acc[r][3] = fmaf(av, b0.w, acc[r][3]);           \
                acc[r][4] = fmaf(av, b1.x, acc[r][4]);           \
                acc[r][5] = fmaf(av, b1.y, acc[r][5]);           \
                acc[r][6] = fmaf(av, b1.z, acc[r][6]);           \
                acc[r][7] = fmaf(av, b1.w, acc[r][7]);
            FMA_ROW(0, a0.x) FMA_ROW(1, a0.y) FMA_ROW(2, a0.z) FMA_ROW(3, a0.w)
            FMA_ROW(4, a1.x) FMA_ROW(5, a1.y) FMA_ROW(6, a1.z) FMA_ROW(7, a1.w)
            #undef FMA_ROW
        }
    }

    // epilogue: activation + bf16 pack + store (8 rows x 2 col-groups of 4)
    #pragma unroll
    for (int rr = 0; rr < 8; ++rr) {
        int m = m0 + ((rr < 4) ? (ri*4 + rr) : (64 + ri*4 + rr - 4));
        #pragma unroll
        for (int t = 0; t < 2; ++t) {
            float v[4];
            #pragma unroll
            for (int j = 0; j < 4; ++j) {
                float tv = acc[rr][t*4+j] + bias[t*4+j];
                float e = __expf(-tv);
                v[j] = (nt == 2) ? e/(1.f+e) : tv/(1.f+e);
            }
            uint2 pk = make_uint2(pack2(v[0], v[1]), pack2(v[2], v[3]));
            int cl = t*64 + ci*4;
            if (nt < 2)
                *(uint2*)(&SC[(size_t)m*256 + nt*128 + cl]) = pk;
            else if (nt == 2)
                *(uint2*)(&OM[(size_t)m*128 + cl]) = pk;
            else
                *(uint2*)(&GATE[(size_t)m*256 + (nt-3)*128 + cl]) = pk;
        }
    }
}

// ---------------- K2: fused fwd+rev complex scans, full-d, bf16 I/O ----------
template<int AXISW, int FIRSTPAIR>
__global__ __launch_bounds__(256) void k_scan2(const u16* __restrict__ SC,
                                               const u16* __restrict__ OM,
                                               const float* __restrict__ trig,
                                               u32* P)
{
    int j = blockIdx.x*256 + threadIdx.x;  // 131072 columns (full d)
    int d = j & 127;
    int col = j >> 7;                      // 0..1023
    int rowbase, stride;
    if (AXISW) { rowbase = (col>>3)*1024 + (col&7); stride = 8; }
    else       { rowbase = col;                     stride = 1024; }

    float cfF = trig[d],     sfF = trig[128+d];
    float cfR = trig[256+d], sfR = trig[384+d];

    long long rowF = rowbase;
    long long rowR = (long long)rowbase + (long long)stride*127;

    float hfr=0.f, hfi=0.f, hrr=0.f, hri=0.f;

    #define SCAN_STEP                                                     \
        u32 uF = *(const u32*)(SC + rowF*256 + 2*d);                      \
        float omF = b2f(OM[rowF*128 + d]);                                \
        u32 uR = *(const u32*)(SC + rowR*256 + 2*d);                      \
        float omR = b2f(OM[rowR*128 + d]);                                \
        float lamF = 1.f - omF, lamR = 1.f - omR;                         \
        float grF = lamF*cfF, giF = lamF*sfF;                             \
        float grR = lamR*cfR, giR = lamR*sfR;                             \
        float ieF = b2f((u16)(uF & 0xffff)), ioF = b2f((u16)(uF >> 16));  \
        float ieR = b2f((u16)(uR & 0xffff)), ioR = b2f((u16)(uR >> 16));  \
        float nfr = fmaf(grF, hfr, fmaf(-giF, hfi, omF*ieF));             \
        float nfi = fmaf(grF, hfi, fmaf( giF, hfr, omF*ioF));             \
        hfr = nfr; hfi = nfi;                                             \
        float nrr = fmaf(grR, hrr, fmaf(-giR, hri, omR*ieR));             \
        float nri = fmaf(grR, hri, fmaf( giR, hrr, omR*ioR));             \
        hrr = nrr; hri = nri;                                             \
        long long piF = rowF*128 + d;                                     \
        long long piR = rowR*128 + d;

    if (FIRSTPAIR) {
        #pragma unroll 4
        for (int t = 0; t < 64; ++t, rowF += stride, rowR -= stride) {
            SCAN_STEP
            P[piF] = pack2(hfr, hfi);
            P[piR] = pack2(hrr, hri);
        }
        #pragma unroll 4
        for (int t = 64; t < 128; ++t, rowF += stride, rowR -= stride) {
            SCAN_STEP
            u32 oF = P[piF];
            P[piF] = pack2(b2f((u16)(oF&0xffff)) + hfr, b2f((u16)(oF>>16)) + hfi);
            u32 oR = P[piR];
            P[piR] = pack2(b2f((u16)(oR&0xffff)) + hrr, b2f((u16)(oR>>16)) + hri);
        }
    } else {
        #pragma unroll 4
        for (int t = 0; t < 128; ++t, rowF += stride, rowR -= stride) {
            SCAN_STEP
            u32 oF = P[piF];
            P[piF] = pack2(b2f((u16)(oF&0xffff)) + hfr, b2f((u16)(oF>>16)) + hfi);
            u32 oR = P[piR];
            P[piR] = pack2(b2f((u16)(oR&0xffff)) + hrr, b2f((u16)(oR>>16)) + hri);
        }
    }
    #undef SCAN_STEP
}

// ---------------- K3: LN + gate + out GEMM; W staged in LDS per 64-k chunk --
#define GETC(v,i) ((i)==0?(v).x:(i)==1?(v).y:(i)==2?(v).z:(v).w)
__global__ __launch_bounds__(256, 3) void k_backend_f32(
    const uint4* __restrict__ P4, const u16* __restrict__ GATE,
    const u16* __restrict__ WoB, const float* __restrict__ ln_w,
    const float* __restrict__ ln_b, const float* __restrict__ bo,
    float* __restrict__ out)
{
    __shared__ u16 fgT[256][68];                // 34 KiB bf16, [channel][row]
    __shared__ u16 wB[64][128];                 // 16 KiB bf16 W chunk [kk][n]
    int tid = threadIdx.x;
    int m0 = blockIdx.x * 64;                   // 2048 blocks
    int r = tid >> 2, q = tid & 3;              // 4 threads per row
    size_t prow4 = (size_t)(m0 + r)*32 + q*8;   // uint4 units (128 u32/row)
    size_t grow = (size_t)(m0 + r)*256;         // u16 units (GATE in ws)

    uint4 ga[4], gb[4];
    #pragma unroll
    for (int g4 = 0; g4 < 4; ++g4) {
        ga[g4] = *(const uint4*)(GATE + grow + q*32 + g4*8);
        gb[g4] = *(const uint4*)(GATE + grow + 128 + q*32 + g4*8);
    }

    uint4 pw[8];                                // 32 packed complex (bf16)
    #pragma unroll
    for (int c4 = 0; c4 < 8; ++c4) pw[c4] = P4[prow4 + c4];

    float fr_[32], fi_[32];
    #pragma unroll
    for (int c4 = 0; c4 < 8; ++c4) {
        #pragma unroll
        for (int w = 0; w < 4; ++w) {
            u32 word = GETC(pw[c4], w);
            int jj = c4*4 + w;
            fr_[jj] = b2f((u16)(word & 0xffff));
            fi_[jj] = b2f((u16)(word >> 16));
        }
    }

    float sum = 0.f, ss = 0.f;
    #pragma unroll
    for (int jj = 0; jj < 32; ++jj) {
        sum += fr_[jj] + fi_[jj];
        ss  += fr_[jj]*fr_[jj] + fi_[jj]*fi_[jj];
    }
    sum += __shfl_xor(sum, 1); sum += __shfl_xor(sum, 2);
    ss  += __shfl_xor(ss, 1);  ss  += __shfl_xor(ss, 2);
    float mu = sum * (1.f/256.f);
    float var = ss * (1.f/256.f) - mu*mu;
    float rstd = rsqrtf(var + 1e-5f);

    #pragma unroll
    for (int jj = 0; jj < 32; ++jj) {
        int pd = q*32 + jj;                     // complex channel 0..127
        int g4 = jj >> 3, e = jj & 7;
        u32 gur = GETC(ga[g4], e>>1), gui = GETC(gb[g4], e>>1);
        float gvr = b2f((u16)((e&1) ? (gur>>16) : (gur&0xffff)));
        float gvi = b2f((u16)((e&1) ? (gui>>16) : (gui&0xffff)));
        float vr = ((fr_[jj] - mu)*rstd*ln_w[pd]     + ln_b[pd])     * gvr;
        float vi = ((fi_[jj] - mu)*rstd*ln_w[128+pd] + ln_b[128+pd]) * gvi;
        fgT[pd][r]     = f2b(vr);
        fgT[128+pd][r] = f2b(vi);
    }

    // out[64][128] = fgT^T @ WoB : 4m x 8n per thread, W LDS-staged per chunk
    int ri = tid >> 4, ci = tid & 15;
    float acc[4][8] = {};
    for (int kc = 0; kc < 4; ++kc) {
        __syncthreads();                        // fgT ready / prev wB reads done
        #pragma unroll
        for (int it = 0; it < 4; ++it) {        // stage 64k x 128n bf16 chunk
            int u = it*256 + tid;               // 1024 uint4 units
            int kk = u >> 4, c8 = u & 15;
            *(uint4*)(&wB[kk][c8*8]) =
                *(const uint4*)(WoB + (size_t)(kc*64 + kk)*128 + c8*8);
        }
        __syncthreads();

        #pragma unroll 4
        for (int kk = 0; kk < 64; ++kk) {
            int k = kc*64 + kk;
            uint2 xr = *(const uint2*)(&fgT[k][ri*4]);
            float xv0 = b2f((u16)(xr.x & 0xffff));
            float xv1 = b2f((u16)(xr.x >> 16));
            float xv2 = b2f((u16)(xr.y & 0xffff));
            float xv3 = b2f((u16)(xr.y >> 16));
            uint4 wv = *(const uint4*)(&wB[kk][ci*8]);
            float w0 = b2f((u16)(wv.x & 0xffff)), w1 = b2f((u16)(wv.x >> 16));
            float w2 = b2f((u16)(wv.y & 0xffff)), w3 = b2f((u16)(wv.y >> 16));
            float w4 = b2f((u16)(wv.z & 0xffff)), w5 = b2f((u16)(wv.z >> 16));
            float w6 = b2f((u16)(wv.w & 0xffff)), w7 = b2f((u16)(wv.w >> 16));
            #define FMA8(i, xv)                                    \
                acc[i][0] = fmaf(xv, w0, acc[i][0]);               \
                acc[i][1] = fmaf(xv, w1, acc[i][1]);               \
                acc[i][2] = fmaf(xv, w2, acc[i][2]);               \
                acc[i][3] = fmaf(xv, w3, acc[i][3]);               \
                acc[i][4] = fmaf(xv, w4, acc[i][4]);               \
                acc[i][5] = fmaf(xv, w5, acc[i][5]);               \
                acc[i][6] = fmaf(xv, w6, acc[i][6]);               \
                acc[i][7] = fmaf(xv, w7, acc[i][7]);
            FMA8(0, xv0) FMA8(1, xv1) FMA8(2, xv2) FMA8(3, xv3)
            #undef FMA8
        }
    }
    #pragma unroll
    for (int i = 0; i < 4; ++i) {
        int m = m0 + ri*4 + i;
        #pragma unroll
        for (int j = 0; j < 8; ++j) {
            int n = ci*8 + j;
            out[(size_t)m*128 + n] = acc[i][j] + bo[n];
        }
    }
}

// ---------------- launch -----------------------------------------------------
extern "C" void kernel_launch(void* const* d_in, const int* in_sizes, int n_in,
                              void* d_out, int out_size, void* d_ws, size_t ws_size,
                              hipStream_t stream)
{
    const float* x      = (const float*)d_in[0];
    const float* W_in   = (const float*)d_in[1];
    const float* b_in   = (const float*)d_in[2];
    const float* W_lam  = (const float*)d_in[3];
    const float* b_lam  = (const float*)d_in[4];
    const float* th_f   = (const float*)d_in[5];
    const float* th_r   = (const float*)d_in[6];
    const float* W_gate = (const float*)d_in[7];
    const float* b_gate = (const float*)d_in[8];
    const float* W_out  = (const float*)d_in[9];
    const float* b_out  = (const float*)d_in[10];
    const float* ln_w   = (const float*)d_in[11];
    const float* ln_b   = (const float*)d_in[12];

    // ws layout: 167,839,744 B <= 168,008,192 B proven-safe envelope
    char* ws = (char*)d_ws;
    u32* P     = (u32*)(ws);                      //  67,108,864 (bf16-pair, full d)
    u16* OM    = (u16*)(ws + 67108864LL);         //  33,554,432 (bf16 om, full d)
    u16* GATE  = (u16*)(ws + 100663296LL);        //  67,108,864 (bf16 gate)
    float* trig= (float*)(ws + 167772160LL);      //   2,048
    u16* WoB   = (u16*)(ws + 167774208LL);        //  65,536 (bf16 W_out)

    // d_out time-shares: SC bf16[M][256] (front->scans) -> out f32[M][128]
    u16* SC   = (u16*)d_out;
    float* out = (float*)d_out;

    hipLaunchKernelGGL(k_prep, dim3(257), dim3(128), 0, stream,
                       th_f, th_r, W_out, trig, WoB);

    hipLaunchKernelGGL(k_front2, dim3(5120), dim3(256), 0, stream,
                       x, W_in, b_in, W_lam, b_lam, W_gate, b_gate,
                       SC, OM, GATE);

    hipLaunchKernelGGL(HIP_KERNEL_NAME(k_scan2<0,1>), dim3(512), dim3(256), 0, stream,
                       SC, OM, trig, P);
    hipLaunchKernelGGL(HIP_KERNEL_NAME(k_scan2<1,0>), dim3(512), dim3(256), 0, stream,
                       SC, OM, trig, P);

    hipLaunchKernelGGL(k_backend_f32, dim3(2048), dim3(256), 0, stream,
                       (const uint4*)P, GATE, WoB, ln_w, ln_b, b_out, out);
}

// Round 14
// 596.614 us; speedup vs baseline: 1.5502x; 1.0055x over previous
//
#include <hip/hip_runtime.h>
#include <hip/hip_bf16.h>
#include <math.h>

// Problem constants
#define HH 128
#define WWW 128
#define BB 8
#define MM (HH*WWW*BB)      // 131072 rows (h,w,b)

typedef unsigned int u32;
typedef unsigned short u16;

__device__ __forceinline__ float b2f(u16 s){ return __uint_as_float(((u32)s)<<16); }
__device__ __forceinline__ u16 f2b(float f){
    u32 u = __float_as_uint(f);
    return (u16)((u + 0x7fffu + ((u>>16)&1u)) >> 16);
}
__device__ __forceinline__ u32 pack2(float lo, float hi){
    return (u32)f2b(lo) | ((u32)f2b(hi)<<16);
}

// ---------------- K0: prep: WB (front weights bf16), WoB, trig --------------
// WB[k][0..256)=W_in, [256..384)=W_lam, [384..640)=W_gate   (bf16, k-major)
__global__ __launch_bounds__(128) void k_prep(
    const float* __restrict__ th_f, const float* __restrict__ th_r,
    const float* __restrict__ W_in, const float* __restrict__ W_lam,
    const float* __restrict__ W_gate, const float* __restrict__ W_out,
    float* __restrict__ trig, u16* __restrict__ WoB, u16* __restrict__ WB)
{
    int t = blockIdx.x*128 + threadIdx.x;     // 897 blocks x 128
    if (t < 81920) {
        int k = t / 640, n = t % 640;
        float v = (n < 256) ? W_in[k*256 + n]
                : (n < 384) ? W_lam[k*128 + (n-256)]
                            : W_gate[k*256 + (n-384)];
        WB[t] = f2b(v);
    } else if (t < 114688) {                  // WoB natural order [k][n]
        int u = t - 81920;
        WoB[u] = f2b(W_out[u]);
    } else if (t < 114816) {
        int d = t - 114688;
        trig[d]     = cosf(th_f[d]); trig[128+d] = sinf(th_f[d]);
        trig[256+d] = cosf(th_r[d]); trig[384+d] = sinf(th_r[d]);
    }
}

// ---------------- K1: front GEMM v4 — x f32 LDS, W bf16 LDS (pre-cast) ------
// Grid 5120 = 1024 m-tiles (outer) x 5 n-tiles (inner). n-tile->dest:
//   nt 0,1 -> SC (silu);  nt 2 -> OM (1-sigmoid);  nt 3,4 -> GATE (silu)
// LDS: xs[32][132] f32 (16.9 KB) + wsb[32][136] u16 (8.7 KB) = 25.6 KB
#define LDT 132
__global__ __launch_bounds__(256, 4) void k_front2(
    const float* __restrict__ x, const u16* __restrict__ WB,
    const float* __restrict__ b_in, const float* __restrict__ b_lam,
    const float* __restrict__ b_gate,
    u16* __restrict__ SC, u16* __restrict__ OM, u16* __restrict__ GATE)
{
    __shared__ float xs[32][LDT];   // [k][row]
    __shared__ u16 wsb[32][136];    // [k][col] bf16
    int tid = threadIdx.x;
    int bid = blockIdx.x;
    int mt = bid / 5, nt = bid % 5;
    int m0 = mt * 128;
    int nw0 = nt * 128;             // column offset into WB's 640

    const float* bsrc = (nt < 2) ? b_in + nt*128
                     : (nt == 2) ? b_lam
                                 : b_gate + (nt-3)*128;

    int ri = tid >> 4, ci = tid & 15;

    float bias[8];
    #pragma unroll
    for (int t = 0; t < 2; ++t)
    #pragma unroll
    for (int j = 0; j < 4; ++j)
        bias[t*4+j] = bsrc[t*64 + ci*4 + j];

    float acc[8][8] = {};

    for (int kc = 0; kc < 4; ++kc) {
        int k0 = kc * 32;
        __syncthreads();                 // protect prev-chunk LDS reads
        #pragma unroll
        for (int it = 0; it < 4; ++it) { // stage x: 128 rows x 32 k (f32)
            int u = it*256 + tid;
            int row = u >> 3, kq = u & 7;
            float4 v = *(const float4*)(x + (size_t)(m0+row)*128 + k0 + kq*4);
            xs[kq*4+0][row] = v.x; xs[kq*4+1][row] = v.y;
            xs[kq*4+2][row] = v.z; xs[kq*4+3][row] = v.w;
        }
        #pragma unroll
        for (int it = 0; it < 2; ++it) { // stage W: 32 k x 128 cols, raw bf16 copy
            int u = it*256 + tid;        // 512 uint4 units
            int krow = u >> 4, c8 = u & 15;
            *(uint4*)(&wsb[krow][c8*8]) =
                *(const uint4*)(WB + (size_t)(k0+krow)*640 + nw0 + c8*8);
        }
        __syncthreads();

        #pragma unroll 4
        for (int k = 0; k < 32; ++k) {
            float4 a0 = *(const float4*)(&xs[k][ri*4]);
            float4 a1 = *(const float4*)(&xs[k][64 + ri*4]);
            uint2 p0 = *(const uint2*)(&wsb[k][ci*4]);
            uint2 p1 = *(const uint2*)(&wsb[k][64 + ci*4]);
            float w0 = b2f((u16)(p0.x & 0xffff)), w1 = b2f((u16)(p0.x >> 16));
            float w2 = b2f((u16)(p0.y & 0xffff)), w3 = b2f((u16)(p0.y >> 16));
            float w4 = b2f((u16)(p1.x & 0xffff)), w5 = b2f((u16)(p1.x >> 16));
            float w6 = b2f((u16)(p1.y & 0xffff)), w7 = b2f((u16)(p1.y >> 16));
            #define FMA_ROW(r, av)                               \
                acc[r][0] = fmaf(av, w0, acc[r][0]);             \
                acc[r][1] = fmaf(av, w1, acc[r][1]);             \
                acc[r][2] = fmaf(av, w2, acc[r][2]);             \
                acc[r][3] = fmaf(av, w3, acc[r][3]);             \
                acc[r][4] = fmaf(av, w4, acc[r][4]);             \
                acc[r][5] = fmaf(av, w5, acc[r][5]);             \
                acc[r][6] = fmaf(av, w6, acc[r][6]);             \
                acc[r][7] = fmaf(av, w7, acc[r][7]);
            FMA_ROW(0, a0.x) FMA_ROW(1, a0.y) FMA_ROW(2, a0.z) FMA_ROW(3, a0.w)
            FMA_ROW(4, a1.x) FMA_ROW(5, a1.y) FMA_ROW(6, a1.z) FMA_ROW(7, a1.w)
            #undef FMA_ROW
        }
    }

    // epilogue: activation + bf16 pack + store (8 rows x 2 col-groups of 4)
    #pragma unroll
    for (int rr = 0; rr < 8; ++rr) {
        int m = m0 + ((rr < 4) ? (ri*4 + rr) : (64 + ri*4 + rr - 4));
        #pragma unroll
        for (int t = 0; t < 2; ++t) {
            float v[4];
            #pragma unroll
            for (int j = 0; j < 4; ++j) {
                float tv = acc[rr][t*4+j] + bias[t*4+j];
                float e = __expf(-tv);
                v[j] = (nt == 2) ? e/(1.f+e) : tv/(1.f+e);
            }
            uint2 pk = make_uint2(pack2(v[0], v[1]), pack2(v[2], v[3]));
            int cl = t*64 + ci*4;
            if (nt < 2)
                *(uint2*)(&SC[(size_t)m*256 + nt*128 + cl]) = pk;
            else if (nt == 2)
                *(uint2*)(&OM[(size_t)m*128 + cl]) = pk;
            else
                *(uint2*)(&GATE[(size_t)m*256 + (nt-3)*128 + cl]) = pk;
        }
    }
}

// ---------------- K2: fused fwd+rev complex scans, full-d, bf16 I/O ----------
template<int AXISW, int FIRSTPAIR>
__global__ __launch_bounds__(256) void k_scan2(const u16* __restrict__ SC,
                                               const u16* __restrict__ OM,
                                               const float* __restrict__ trig,
                                               u32* P)
{
    int j = blockIdx.x*256 + threadIdx.x;  // 131072 columns (full d)
    int d = j & 127;
    int col = j >> 7;                      // 0..1023
    int rowbase, stride;
    if (AXISW) { rowbase = (col>>3)*1024 + (col&7); stride = 8; }
    else       { rowbase = col;                     stride = 1024; }

    float cfF = trig[d],     sfF = trig[128+d];
    float cfR = trig[256+d], sfR = trig[384+d];

    long long rowF = rowbase;
    long long rowR = (long long)rowbase + (long long)stride*127;

    float hfr=0.f, hfi=0.f, hrr=0.f, hri=0.f;

    #define SCAN_STEP                                                     \
        u32 uF = *(const u32*)(SC + rowF*256 + 2*d);                      \
        float omF = b2f(OM[rowF*128 + d]);                                \
        u32 uR = *(const u32*)(SC + rowR*256 + 2*d);                      \
        float omR = b2f(OM[rowR*128 + d]);                                \
        float lamF = 1.f - omF, lamR = 1.f - omR;                         \
        float grF = lamF*cfF, giF = lamF*sfF;                             \
        float grR = lamR*cfR, giR = lamR*sfR;                             \
        float ieF = b2f((u16)(uF & 0xffff)), ioF = b2f((u16)(uF >> 16));  \
        float ieR = b2f((u16)(uR & 0xffff)), ioR = b2f((u16)(uR >> 16));  \
        float nfr = fmaf(grF, hfr, fmaf(-giF, hfi, omF*ieF));             \
        float nfi = fmaf(grF, hfi, fmaf( giF, hfr, omF*ioF));             \
        hfr = nfr; hfi = nfi;                                             \
        float nrr = fmaf(grR, hrr, fmaf(-giR, hri, omR*ieR));             \
        float nri = fmaf(grR, hri, fmaf( giR, hrr, omR*ioR));             \
        hrr = nrr; hri = nri;                                             \
        long long piF = rowF*128 + d;                                     \
        long long piR = rowR*128 + d;

    if (FIRSTPAIR) {
        #pragma unroll 4
        for (int t = 0; t < 64; ++t, rowF += stride, rowR -= stride) {
            SCAN_STEP
            P[piF] = pack2(hfr, hfi);
            P[piR] = pack2(hrr, hri);
        }
        #pragma unroll 4
        for (int t = 64; t < 128; ++t, rowF += stride, rowR -= stride) {
            SCAN_STEP
            u32 oF = P[piF];
            P[piF] = pack2(b2f((u16)(oF&0xffff)) + hfr, b2f((u16)(oF>>16)) + hfi);
            u32 oR = P[piR];
            P[piR] = pack2(b2f((u16)(oR&0xffff)) + hrr, b2f((u16)(oR>>16)) + hri);
        }
    } else {
        #pragma unroll 4
        for (int t = 0; t < 128; ++t, rowF += stride, rowR -= stride) {
            SCAN_STEP
            u32 oF = P[piF];
            P[piF] = pack2(b2f((u16)(oF&0xffff)) + hfr, b2f((u16)(oF>>16)) + hfi);
            u32 oR = P[piR];
            P[piR] = pack2(b2f((u16)(oR&0xffff)) + hrr, b2f((u16)(oR>>16)) + hri);
        }
    }
    #undef SCAN_STEP
}

// ---------------- K3: LN + gate + out GEMM; W staged in LDS per 64-k chunk --
#define GETC(v,i) ((i)==0?(v).x:(i)==1?(v).y:(i)==2?(v).z:(v).w)
__global__ __launch_bounds__(256, 3) void k_backend_f32(
    const uint4* __restrict__ P4, const u16* __restrict__ GATE,
    const u16* __restrict__ WoB, const float* __restrict__ ln_w,
    const float* __restrict__ ln_b, const float* __restrict__ bo,
    float* __restrict__ out)
{
    __shared__ u16 fgT[256][68];                // 34 KiB bf16, [channel][row]
    __shared__ u16 wB[64][128];                 // 16 KiB bf16 W chunk [kk][n]
    int tid = threadIdx.x;
    int m0 = blockIdx.x * 64;                   // 2048 blocks
    int r = tid >> 2, q = tid & 3;              // 4 threads per row
    size_t prow4 = (size_t)(m0 + r)*32 + q*8;   // uint4 units (128 u32/row)
    size_t grow = (size_t)(m0 + r)*256;         // u16 units (GATE in ws)

    uint4 ga[4], gb[4];
    #pragma unroll
    for (int g4 = 0; g4 < 4; ++g4) {
        ga[g4] = *(const uint4*)(GATE + grow + q*32 + g4*8);
        gb[g4] = *(const uint4*)(GATE + grow + 128 + q*32 + g4*8);
    }

    uint4 pw[8];                                // 32 packed complex (bf16)
    #pragma unroll
    for (int c4 = 0; c4 < 8; ++c4) pw[c4] = P4[prow4 + c4];

    float fr_[32], fi_[32];
    #pragma unroll
    for (int c4 = 0; c4 < 8; ++c4) {
        #pragma unroll
        for (int w = 0; w < 4; ++w) {
            u32 word = GETC(pw[c4], w);
            int jj = c4*4 + w;
            fr_[jj] = b2f((u16)(word & 0xffff));
            fi_[jj] = b2f((u16)(word >> 16));
        }
    }

    float sum = 0.f, ss = 0.f;
    #pragma unroll
    for (int jj = 0; jj < 32; ++jj) {
        sum += fr_[jj] + fi_[jj];
        ss  += fr_[jj]*fr_[jj] + fi_[jj]*fi_[jj];
    }
    sum += __shfl_xor(sum, 1); sum += __shfl_xor(sum, 2);
    ss  += __shfl_xor(ss, 1);  ss  += __shfl_xor(ss, 2);
    float mu = sum * (1.f/256.f);
    float var = ss * (1.f/256.f) - mu*mu;
    float rstd = rsqrtf(var + 1e-5f);

    #pragma unroll
    for (int jj = 0; jj < 32; ++jj) {
        int pd = q*32 + jj;                     // complex channel 0..127
        int g4 = jj >> 3, e = jj & 7;
        u32 gur = GETC(ga[g4], e>>1), gui = GETC(gb[g4], e>>1);
        float gvr = b2f((u16)((e&1) ? (gur>>16) : (gur&0xffff)));
        float gvi = b2f((u16)((e&1) ? (gui>>16) : (gui&0xffff)));
        float vr = ((fr_[jj] - mu)*rstd*ln_w[pd]     + ln_b[pd])     * gvr;
        float vi = ((fi_[jj] - mu)*rstd*ln_w[128+pd] + ln_b[128+pd]) * gvi;
        fgT[pd][r]     = f2b(vr);
        fgT[128+pd][r] = f2b(vi);
    }

    // out[64][128] = fgT^T @ WoB : 4m x 8n per thread, W LDS-staged per chunk
    int ri = tid >> 4, ci = tid & 15;
    float acc[4][8] = {};
    for (int kc = 0; kc < 4; ++kc) {
        __syncthreads();                        // fgT ready / prev wB reads done
        #pragma unroll
        for (int it = 0; it < 4; ++it) {        // stage 64k x 128n bf16 chunk
            int u = it*256 + tid;               // 1024 uint4 units
            int kk = u >> 4, c8 = u & 15;
            *(uint4*)(&wB[kk][c8*8]) =
                *(const uint4*)(WoB + (size_t)(kc*64 + kk)*128 + c8*8);
        }
        __syncthreads();

        #pragma unroll 4
        for (int kk = 0; kk < 64; ++kk) {
            int k = kc*64 + kk;
            uint2 xr = *(const uint2*)(&fgT[k][ri*4]);
            float xv0 = b2f((u16)(xr.x & 0xffff));
            float xv1 = b2f((u16)(xr.x >> 16));
            float xv2 = b2f((u16)(xr.y & 0xffff));
            float xv3 = b2f((u16)(xr.y >> 16));
            uint4 wv = *(const uint4*)(&wB[kk][ci*8]);
            float w0 = b2f((u16)(wv.x & 0xffff)), w1 = b2f((u16)(wv.x >> 16));
            float w2 = b2f((u16)(wv.y & 0xffff)), w3 = b2f((u16)(wv.y >> 16));
            float w4 = b2f((u16)(wv.z & 0xffff)), w5 = b2f((u16)(wv.z >> 16));
            float w6 = b2f((u16)(wv.w & 0xffff)), w7 = b2f((u16)(wv.w >> 16));
            #define FMA8(i, xv)                                    \
                acc[i][0] = fmaf(xv, w0, acc[i][0]);               \
                acc[i][1] = fmaf(xv, w1, acc[i][1]);               \
                acc[i][2] = fmaf(xv, w2, acc[i][2]);               \
                acc[i][3] = fmaf(xv, w3, acc[i][3]);               \
                acc[i][4] = fmaf(xv, w4, acc[i][4]);               \
                acc[i][5] = fmaf(xv, w5, acc[i][5]);               \
                acc[i][6] = fmaf(xv, w6, acc[i][6]);               \
                acc[i][7] = fmaf(xv, w7, acc[i][7]);
            FMA8(0, xv0) FMA8(1, xv1) FMA8(2, xv2) FMA8(3, xv3)
            #undef FMA8
        }
    }
    #pragma unroll
    for (int i = 0; i < 4; ++i) {
        int m = m0 + ri*4 + i;
        #pragma unroll
        for (int j = 0; j < 8; ++j) {
            int n = ci*8 + j;
            out[(size_t)m*128 + n] = acc[i][j] + bo[n];
        }
    }
}

// ---------------- launch -----------------------------------------------------
extern "C" void kernel_launch(void* const* d_in, const int* in_sizes, int n_in,
                              void* d_out, int out_size, void* d_ws, size_t ws_size,
                              hipStream_t stream)
{
    const float* x      = (const float*)d_in[0];
    const float* W_in   = (const float*)d_in[1];
    const float* b_in   = (const float*)d_in[2];
    const float* W_lam  = (const float*)d_in[3];
    const float* b_lam  = (const float*)d_in[4];
    const float* th_f   = (const float*)d_in[5];
    const float* th_r   = (const float*)d_in[6];
    const float* W_gate = (const float*)d_in[7];
    const float* b_gate = (const float*)d_in[8];
    const float* W_out  = (const float*)d_in[9];
    const float* b_out  = (const float*)d_in[10];
    const float* ln_w   = (const float*)d_in[11];
    const float* ln_b   = (const float*)d_in[12];

    // ws layout: 168,003,584 B <= 168,008,192 B proven-safe envelope
    char* ws = (char*)d_ws;
    u32* P     = (u32*)(ws);                      //  67,108,864 (bf16-pair, full d)
    u16* OM    = (u16*)(ws + 67108864LL);         //  33,554,432 (bf16 om, full d)
    u16* GATE  = (u16*)(ws + 100663296LL);        //  67,108,864 (bf16 gate)
    float* trig= (float*)(ws + 167772160LL);      //   2,048
    u16* WoB   = (u16*)(ws + 167774208LL);        //  65,536 (bf16 W_out)
    u16* WB    = (u16*)(ws + 167839744LL);        // 163,840 (bf16 front weights)

    // d_out time-shares: SC bf16[M][256] (front->scans) -> out f32[M][128]
    u16* SC   = (u16*)d_out;
    float* out = (float*)d_out;

    hipLaunchKernelGGL(k_prep, dim3(897), dim3(128), 0, stream,
                       th_f, th_r, W_in, W_lam, W_gate, W_out, trig, WoB, WB);

    hipLaunchKernelGGL(k_front2, dim3(5120), dim3(256), 0, stream,
                       x, WB, b_in, b_lam, b_gate, SC, OM, GATE);

    hipLaunchKernelGGL(HIP_KERNEL_NAME(k_scan2<0,1>), dim3(512), dim3(256), 0, stream,
                       SC, OM, trig, P);
    hipLaunchKernelGGL(HIP_KERNEL_NAME(k_scan2<1,0>), dim3(512), dim3(256), 0, stream,
                       SC, OM, trig, P);

    hipLaunchKernelGGL(k_backend_f32, dim3(2048), dim3(256), 0, stream,
                       (const uint4*)P, GATE, WoB, ln_w, ln_b, b_out, out);
}

// Round 15
// 591.748 us; speedup vs baseline: 1.5629x; 1.0082x over previous
//
#include <hip/hip_runtime.h>
#include <hip/hip_bf16.h>
#include <math.h>

// Problem constants
#define HH 128
#define WWW 128
#define BB 8
#define MM (HH*WWW*BB)      // 131072 rows (h,w,b)

typedef unsigned int u32;
typedef unsigned short u16;

__device__ __forceinline__ float b2f(u16 s){ return __uint_as_float(((u32)s)<<16); }
__device__ __forceinline__ u16 f2b(float f){
    u32 u = __float_as_uint(f);
    return (u16)((u + 0x7fffu + ((u>>16)&1u)) >> 16);
}
__device__ __forceinline__ u32 pack2(float lo, float hi){
    return (u32)f2b(lo) | ((u32)f2b(hi)<<16);
}

// ---------------- K0: prep: WB (front weights bf16), WoB, trig --------------
// WB[k][0..256)=W_in, [256..384)=W_lam, [384..640)=W_gate   (bf16, k-major)
__global__ __launch_bounds__(128) void k_prep(
    const float* __restrict__ th_f, const float* __restrict__ th_r,
    const float* __restrict__ W_in, const float* __restrict__ W_lam,
    const float* __restrict__ W_gate, const float* __restrict__ W_out,
    float* __restrict__ trig, u16* __restrict__ WoB, u16* __restrict__ WB)
{
    int t = blockIdx.x*128 + threadIdx.x;     // 897 blocks x 128
    if (t < 81920) {
        int k = t / 640, n = t % 640;
        float v = (n < 256) ? W_in[k*256 + n]
                : (n < 384) ? W_lam[k*128 + (n-256)]
                            : W_gate[k*256 + (n-384)];
        WB[t] = f2b(v);
    } else if (t < 114688) {                  // WoB natural order [k][n]
        int u = t - 81920;
        WoB[u] = f2b(W_out[u]);
    } else if (t < 114816) {
        int d = t - 114688;
        trig[d]     = cosf(th_f[d]); trig[128+d] = sinf(th_f[d]);
        trig[256+d] = cosf(th_r[d]); trig[384+d] = sinf(th_r[d]);
    }
}

// ---------------- K1: front GEMM v4 — x f32 LDS, W bf16 LDS (pre-cast) ------
// Grid 5120 = 1024 m-tiles (outer) x 5 n-tiles (inner). n-tile->dest:
//   nt 0,1 -> SC (silu);  nt 2 -> OM (1-sigmoid);  nt 3,4 -> GATE (silu)
// LDS: xs[32][132] f32 (16.9 KB) + wsb[32][136] u16 (8.7 KB) = 25.6 KB
// launch_bounds (256,3): ~170 VGPR cap -> no spill (r14 spilled at the 128 cap:
// WRITE_SIZE 245.8 MB vs 160 MB of real output).
#define LDT 132
__global__ __launch_bounds__(256, 3) void k_front2(
    const float* __restrict__ x, const u16* __restrict__ WB,
    const float* __restrict__ b_in, const float* __restrict__ b_lam,
    const float* __restrict__ b_gate,
    u16* __restrict__ SC, u16* __restrict__ OM, u16* __restrict__ GATE)
{
    __shared__ float xs[32][LDT];   // [k][row]
    __shared__ u16 wsb[32][136];    // [k][col] bf16
    int tid = threadIdx.x;
    int bid = blockIdx.x;
    int mt = bid / 5, nt = bid % 5;
    int m0 = mt * 128;
    int nw0 = nt * 128;             // column offset into WB's 640

    const float* bsrc = (nt < 2) ? b_in + nt*128
                     : (nt == 2) ? b_lam
                                 : b_gate + (nt-3)*128;

    int ri = tid >> 4, ci = tid & 15;

    float bias[8];
    #pragma unroll
    for (int t = 0; t < 2; ++t)
    #pragma unroll
    for (int j = 0; j < 4; ++j)
        bias[t*4+j] = bsrc[t*64 + ci*4 + j];

    float acc[8][8] = {};

    for (int kc = 0; kc < 4; ++kc) {
        int k0 = kc * 32;
        __syncthreads();                 // protect prev-chunk LDS reads
        #pragma unroll
        for (int it = 0; it < 4; ++it) { // stage x: 128 rows x 32 k (f32)
            int u = it*256 + tid;
            int row = u >> 3, kq = u & 7;
            float4 v = *(const float4*)(x + (size_t)(m0+row)*128 + k0 + kq*4);
            xs[kq*4+0][row] = v.x; xs[kq*4+1][row] = v.y;
            xs[kq*4+2][row] = v.z; xs[kq*4+3][row] = v.w;
        }
        #pragma unroll
        for (int it = 0; it < 2; ++it) { // stage W: 32 k x 128 cols, raw bf16 copy
            int u = it*256 + tid;        // 512 uint4 units
            int krow = u >> 4, c8 = u & 15;
            *(uint4*)(&wsb[krow][c8*8]) =
                *(const uint4*)(WB + (size_t)(k0+krow)*640 + nw0 + c8*8);
        }
        __syncthreads();

        #pragma unroll 4
        for (int k = 0; k < 32; ++k) {
            float4 a0 = *(const float4*)(&xs[k][ri*4]);
            float4 a1 = *(const float4*)(&xs[k][64 + ri*4]);
            uint2 p0 = *(const uint2*)(&wsb[k][ci*4]);
            uint2 p1 = *(const uint2*)(&wsb[k][64 + ci*4]);
            float w0 = b2f((u16)(p0.x & 0xffff)), w1 = b2f((u16)(p0.x >> 16));
            float w2 = b2f((u16)(p0.y & 0xffff)), w3 = b2f((u16)(p0.y >> 16));
            float w4 = b2f((u16)(p1.x & 0xffff)), w5 = b2f((u16)(p1.x >> 16));
            float w6 = b2f((u16)(p1.y & 0xffff)), w7 = b2f((u16)(p1.y >> 16));
            #define FMA_ROW(r, av)                               \
                acc[r][0] = fmaf(av, w0, acc[r][0]);             \
                acc[r][1] = fmaf(av, w1, acc[r][1]);             \
                acc[r][2] = fmaf(av, w2, acc[r][2]);             \
                acc[r][3] = fmaf(av, w3, acc[r][3]);             \
                acc[r][4] = fmaf(av, w4, acc[r][4]);             \
                acc[r][5] = fmaf(av, w5, acc[r][5]);             \
                acc[r][6] = fmaf(av, w6, acc[r][6]);             \
                acc[r][7] = fmaf(av, w7, acc[r][7]);
            FMA_ROW(0, a0.x) FMA_ROW(1, a0.y) FMA_ROW(2, a0.z) FMA_ROW(3, a0.w)
            FMA_ROW(4, a1.x) FMA_ROW(5, a1.y) FMA_ROW(6, a1.z) FMA_ROW(7, a1.w)
            #undef FMA_ROW
        }
    }

    // epilogue: activation + bf16 pack + store (8 rows x 2 col-groups of 4)
    #pragma unroll
    for (int rr = 0; rr < 8; ++rr) {
        int m = m0 + ((rr < 4) ? (ri*4 + rr) : (64 + ri*4 + rr - 4));
        #pragma unroll
        for (int t = 0; t < 2; ++t) {
            float v[4];
            #pragma unroll
            for (int j = 0; j < 4; ++j) {
                float tv = acc[rr][t*4+j] + bias[t*4+j];
                float e = __expf(-tv);
                v[j] = (nt == 2) ? e/(1.f+e) : tv/(1.f+e);
            }
            uint2 pk = make_uint2(pack2(v[0], v[1]), pack2(v[2], v[3]));
            int cl = t*64 + ci*4;
            if (nt < 2)
                *(uint2*)(&SC[(size_t)m*256 + nt*128 + cl]) = pk;
            else if (nt == 2)
                *(uint2*)(&OM[(size_t)m*128 + cl]) = pk;
            else
                *(uint2*)(&GATE[(size_t)m*256 + (nt-3)*128 + cl]) = pk;
        }
    }
}

// ---------------- K2: fused fwd+rev complex scans, full-d, bf16 I/O ----------
template<int AXISW, int FIRSTPAIR>
__global__ __launch_bounds__(256) void k_scan2(const u16* __restrict__ SC,
                                               const u16* __restrict__ OM,
                                               const float* __restrict__ trig,
                                               u32* P)
{
    int j = blockIdx.x*256 + threadIdx.x;  // 131072 columns (full d)
    int d = j & 127;
    int col = j >> 7;                      // 0..1023
    int rowbase, stride;
    if (AXISW) { rowbase = (col>>3)*1024 + (col&7); stride = 8; }
    else       { rowbase = col;                     stride = 1024; }

    float cfF = trig[d],     sfF = trig[128+d];
    float cfR = trig[256+d], sfR = trig[384+d];

    long long rowF = rowbase;
    long long rowR = (long long)rowbase + (long long)stride*127;

    float hfr=0.f, hfi=0.f, hrr=0.f, hri=0.f;

    #define SCAN_STEP                                                     \
        u32 uF = *(const u32*)(SC + rowF*256 + 2*d);                      \
        float omF = b2f(OM[rowF*128 + d]);                                \
        u32 uR = *(const u32*)(SC + rowR*256 + 2*d);                      \
        float omR = b2f(OM[rowR*128 + d]);                                \
        float lamF = 1.f - omF, lamR = 1.f - omR;                         \
        float grF = lamF*cfF, giF = lamF*sfF;                             \
        float grR = lamR*cfR, giR = lamR*sfR;                             \
        float ieF = b2f((u16)(uF & 0xffff)), ioF = b2f((u16)(uF >> 16));  \
        float ieR = b2f((u16)(uR & 0xffff)), ioR = b2f((u16)(uR >> 16));  \
        float nfr = fmaf(grF, hfr, fmaf(-giF, hfi, omF*ieF));             \
        float nfi = fmaf(grF, hfi, fmaf( giF, hfr, omF*ioF));             \
        hfr = nfr; hfi = nfi;                                             \
        float nrr = fmaf(grR, hrr, fmaf(-giR, hri, omR*ieR));             \
        float nri = fmaf(grR, hri, fmaf( giR, hrr, omR*ioR));             \
        hrr = nrr; hri = nri;                                             \
        long long piF = rowF*128 + d;                                     \
        long long piR = rowR*128 + d;

    if (FIRSTPAIR) {
        #pragma unroll 4
        for (int t = 0; t < 64; ++t, rowF += stride, rowR -= stride) {
            SCAN_STEP
            P[piF] = pack2(hfr, hfi);
            P[piR] = pack2(hrr, hri);
        }
        #pragma unroll 4
        for (int t = 64; t < 128; ++t, rowF += stride, rowR -= stride) {
            SCAN_STEP
            u32 oF = P[piF];
            P[piF] = pack2(b2f((u16)(oF&0xffff)) + hfr, b2f((u16)(oF>>16)) + hfi);
            u32 oR = P[piR];
            P[piR] = pack2(b2f((u16)(oR&0xffff)) + hrr, b2f((u16)(oR>>16)) + hri);
        }
    } else {
        #pragma unroll 4
        for (int t = 0; t < 128; ++t, rowF += stride, rowR -= stride) {
            SCAN_STEP
            u32 oF = P[piF];
            P[piF] = pack2(b2f((u16)(oF&0xffff)) + hfr, b2f((u16)(oF>>16)) + hfi);
            u32 oR = P[piR];
            P[piR] = pack2(b2f((u16)(oR&0xffff)) + hrr, b2f((u16)(oR>>16)) + hri);
        }
    }
    #undef SCAN_STEP
}

// ---------------- K3: LN + gate + out GEMM; W staged in LDS per 64-k chunk --
#define GETC(v,i) ((i)==0?(v).x:(i)==1?(v).y:(i)==2?(v).z:(v).w)
__global__ __launch_bounds__(256, 3) void k_backend_f32(
    const uint4* __restrict__ P4, const u16* __restrict__ GATE,
    const u16* __restrict__ WoB, const float* __restrict__ ln_w,
    const float* __restrict__ ln_b, const float* __restrict__ bo,
    float* __restrict__ out)
{
    __shared__ u16 fgT[256][68];                // 34 KiB bf16, [channel][row]
    __shared__ u16 wB[64][128];                 // 16 KiB bf16 W chunk [kk][n]
    int tid = threadIdx.x;
    int m0 = blockIdx.x * 64;                   // 2048 blocks
    int r = tid >> 2, q = tid & 3;              // 4 threads per row
    size_t prow4 = (size_t)(m0 + r)*32 + q*8;   // uint4 units (128 u32/row)
    size_t grow = (size_t)(m0 + r)*256;         // u16 units (GATE in ws)

    uint4 ga[4], gb[4];
    #pragma unroll
    for (int g4 = 0; g4 < 4; ++g4) {
        ga[g4] = *(const uint4*)(GATE + grow + q*32 + g4*8);
        gb[g4] = *(const uint4*)(GATE + grow + 128 + q*32 + g4*8);
    }

    uint4 pw[8];                                // 32 packed complex (bf16)
    #pragma unroll
    for (int c4 = 0; c4 < 8; ++c4) pw[c4] = P4[prow4 + c4];

    float fr_[32], fi_[32];
    #pragma unroll
    for (int c4 = 0; c4 < 8; ++c4) {
        #pragma unroll
        for (int w = 0; w < 4; ++w) {
            u32 word = GETC(pw[c4], w);
            int jj = c4*4 + w;
            fr_[jj] = b2f((u16)(word & 0xffff));
            fi_[jj] = b2f((u16)(word >> 16));
        }
    }

    float sum = 0.f, ss = 0.f;
    #pragma unroll
    for (int jj = 0; jj < 32; ++jj) {
        sum += fr_[jj] + fi_[jj];
        ss  += fr_[jj]*fr_[jj] + fi_[jj]*fi_[jj];
    }
    sum += __shfl_xor(sum, 1); sum += __shfl_xor(sum, 2);
    ss  += __shfl_xor(ss, 1);  ss  += __shfl_xor(ss, 2);
    float mu = sum * (1.f/256.f);
    float var = ss * (1.f/256.f) - mu*mu;
    float rstd = rsqrtf(var + 1e-5f);

    #pragma unroll
    for (int jj = 0; jj < 32; ++jj) {
        int pd = q*32 + jj;                     // complex channel 0..127
        int g4 = jj >> 3, e = jj & 7;
        u32 gur = GETC(ga[g4], e>>1), gui = GETC(gb[g4], e>>1);
        float gvr = b2f((u16)((e&1) ? (gur>>16) : (gur&0xffff)));
        float gvi = b2f((u16)((e&1) ? (gui>>16) : (gui&0xffff)));
        float vr = ((fr_[jj] - mu)*rstd*ln_w[pd]     + ln_b[pd])     * gvr;
        float vi = ((fi_[jj] - mu)*rstd*ln_w[128+pd] + ln_b[128+pd]) * gvi;
        fgT[pd][r]     = f2b(vr);
        fgT[128+pd][r] = f2b(vi);
    }

    // out[64][128] = fgT^T @ WoB : 4m x 8n per thread, W LDS-staged per chunk
    int ri = tid >> 4, ci = tid & 15;
    float acc[4][8] = {};
    for (int kc = 0; kc < 4; ++kc) {
        __syncthreads();                        // fgT ready / prev wB reads done
        #pragma unroll
        for (int it = 0; it < 4; ++it) {        // stage 64k x 128n bf16 chunk
            int u = it*256 + tid;               // 1024 uint4 units
            int kk = u >> 4, c8 = u & 15;
            *(uint4*)(&wB[kk][c8*8]) =
                *(const uint4*)(WoB + (size_t)(kc*64 + kk)*128 + c8*8);
        }
        __syncthreads();

        #pragma unroll 4
        for (int kk = 0; kk < 64; ++kk) {
            int k = kc*64 + kk;
            uint2 xr = *(const uint2*)(&fgT[k][ri*4]);
            float xv0 = b2f((u16)(xr.x & 0xffff));
            float xv1 = b2f((u16)(xr.x >> 16));
            float xv2 = b2f((u16)(xr.y & 0xffff));
            float xv3 = b2f((u16)(xr.y >> 16));
            uint4 wv = *(const uint4*)(&wB[kk][ci*8]);
            float w0 = b2f((u16)(wv.x & 0xffff)), w1 = b2f((u16)(wv.x >> 16));
            float w2 = b2f((u16)(wv.y & 0xffff)), w3 = b2f((u16)(wv.y >> 16));
            float w4 = b2f((u16)(wv.z & 0xffff)), w5 = b2f((u16)(wv.z >> 16));
            float w6 = b2f((u16)(wv.w & 0xffff)), w7 = b2f((u16)(wv.w >> 16));
            #define FMA8(i, xv)                                    \
                acc[i][0] = fmaf(xv, w0, acc[i][0]);               \
                acc[i][1] = fmaf(xv, w1, acc[i][1]);               \
                acc[i][2] = fmaf(xv, w2, acc[i][2]);               \
                acc[i][3] = fmaf(xv, w3, acc[i][3]);               \
                acc[i][4] = fmaf(xv, w4, acc[i][4]);               \
                acc[i][5] = fmaf(xv, w5, acc[i][5]);               \
                acc[i][6] = fmaf(xv, w6, acc[i][6]);               \
                acc[i][7] = fmaf(xv, w7, acc[i][7]);
            FMA8(0, xv0) FMA8(1, xv1) FMA8(2, xv2) FMA8(3, xv3)
            #undef FMA8
        }
    }
    #pragma unroll
    for (int i = 0; i < 4; ++i) {
        int m = m0 + ri*4 + i;
        #pragma unroll
        for (int j = 0; j < 8; ++j) {
            int n = ci*8 + j;
            out[(size_t)m*128 + n] = acc[i][j] + bo[n];
        }
    }
}

// ---------------- launch -----------------------------------------------------
extern "C" void kernel_launch(void* const* d_in, const int* in_sizes, int n_in,
                              void* d_out, int out_size, void* d_ws, size_t ws_size,
                              hipStream_t stream)
{
    const float* x      = (const float*)d_in[0];
    const float* W_in   = (const float*)d_in[1];
    const float* b_in   = (const float*)d_in[2];
    const float* W_lam  = (const float*)d_in[3];
    const float* b_lam  = (const float*)d_in[4];
    const float* th_f   = (const float*)d_in[5];
    const float* th_r   = (const float*)d_in[6];
    const float* W_gate = (const float*)d_in[7];
    const float* b_gate = (const float*)d_in[8];
    const float* W_out  = (const float*)d_in[9];
    const float* b_out  = (const float*)d_in[10];
    const float* ln_w   = (const float*)d_in[11];
    const float* ln_b   = (const float*)d_in[12];

    // ws layout: 168,003,584 B <= 168,008,192 B proven-safe envelope
    char* ws = (char*)d_ws;
    u32* P     = (u32*)(ws);                      //  67,108,864 (bf16-pair, full d)
    u16* OM    = (u16*)(ws + 67108864LL);         //  33,554,432 (bf16 om, full d)
    u16* GATE  = (u16*)(ws + 100663296LL);        //  67,108,864 (bf16 gate)
    float* trig= (float*)(ws + 167772160LL);      //   2,048
    u16* WoB   = (u16*)(ws + 167774208LL);        //  65,536 (bf16 W_out)
    u16* WB    = (u16*)(ws + 167839744LL);        // 163,840 (bf16 front weights)

    // d_out time-shares: SC bf16[M][256] (front->scans) -> out f32[M][128]
    u16* SC   = (u16*)d_out;
    float* out = (float*)d_out;

    hipLaunchKernelGGL(k_prep, dim3(897), dim3(128), 0, stream,
                       th_f, th_r, W_in, W_lam, W_gate, W_out, trig, WoB, WB);

    hipLaunchKernelGGL(k_front2, dim3(5120), dim3(256), 0, stream,
                       x, WB, b_in, b_lam, b_gate, SC, OM, GATE);

    hipLaunchKernelGGL(HIP_KERNEL_NAME(k_scan2<0,1>), dim3(512), dim3(256), 0, stream,
                       SC, OM, trig, P);
    hipLaunchKernelGGL(HIP_KERNEL_NAME(k_scan2<1,0>), dim3(512), dim3(256), 0, stream,
                       SC, OM, trig, P);

    hipLaunchKernelGGL(k_backend_f32, dim3(2048), dim3(256), 0, stream,
                       (const uint4*)P, GATE, WoB, ln_w, ln_b, b_out, out);
}

// Round 16
// 412.408 us; speedup vs baseline: 2.2426x; 1.4349x over previous
//
#include <hip/hip_runtime.h>
#include <hip/hip_bf16.h>
#include <math.h>

// Problem constants
#define HH 128
#define WWW 128
#define BB 8
#define MM (HH*WWW*BB)      // 131072 rows (h,w,b)

typedef unsigned int u32;
typedef unsigned short u16;

using frag_ab = __attribute__((ext_vector_type(8))) short;   // 8 bf16
using frag_cd = __attribute__((ext_vector_type(4))) float;   // 4 f32

__device__ __forceinline__ float b2f(u16 s){ return __uint_as_float(((u32)s)<<16); }
__device__ __forceinline__ u16 f2b(float f){
    u32 u = __float_as_uint(f);
    return (u16)((u + 0x7fffu + ((u>>16)&1u)) >> 16);
}
__device__ __forceinline__ u32 pack2(float lo, float hi){
    return (u32)f2b(lo) | ((u32)f2b(hi)<<16);
}

// ---------------- K0: prep: WtB (front weights bf16, n-major), WoB, trig ----
// WtB[n][k], n: 0-255 W_in | 256-383 W_lam | 384-639 W_gate
__global__ __launch_bounds__(128) void k_prep(
    const float* __restrict__ th_f, const float* __restrict__ th_r,
    const float* __restrict__ W_in, const float* __restrict__ W_lam,
    const float* __restrict__ W_gate, const float* __restrict__ W_out,
    float* __restrict__ trig, u16* __restrict__ WoB, u16* __restrict__ WtB)
{
    int t = blockIdx.x*128 + threadIdx.x;     // 897 blocks x 128
    if (t < 81920) {
        int n = t >> 7, k = t & 127;
        float v = (n < 256) ? W_in[k*256 + n]
                : (n < 384) ? W_lam[k*128 + (n-256)]
                            : W_gate[k*256 + (n-384)];
        WtB[t] = f2b(v);
    } else if (t < 114688) {                  // WoB natural order [k][n]
        int u = t - 81920;
        WoB[u] = f2b(W_out[u]);
    } else if (t < 114816) {
        int d = t - 114688;
        trig[d]     = cosf(th_f[d]); trig[128+d] = sinf(th_f[d]);
        trig[256+d] = cosf(th_r[d]); trig[384+d] = sinf(th_r[d]);
    }
}

// ---------------- K1: front GEMM via MFMA (r1 structure, bisection-cleared) --
// One block per 128-row m-tile; As staged once (f32->bf16, XOR-swizzled);
// loop 5 n-subtiles with raw bf16 Bs staging from WtB[n][k].
//   nt 0,1 -> SC (silu);  nt 2 -> OM (1-sigmoid);  nt 3,4 -> GATE (silu)
__global__ __launch_bounds__(256) void k_front_mfma(
    const float* __restrict__ x, const u16* __restrict__ WtB,
    const float* __restrict__ b_in, const float* __restrict__ b_lam,
    const float* __restrict__ b_gate,
    u16* __restrict__ SC, u16* __restrict__ OM, u16* __restrict__ GATE)
{
    __shared__ __align__(16) char As[32768];   // 128 rows x 256B, XOR-swizzled
    __shared__ __align__(16) char Bs[32768];

    int m0 = blockIdx.x * 128;                 // 1024 blocks
    int tid = threadIdx.x;

    #pragma unroll
    for (int it = 0; it < 8; ++it) {           // stage A once: f32 x -> bf16
        int u = it*256 + tid;                  // 2048 16B units
        int row = u >> 4, c16 = u & 15;
        const float* src = x + (size_t)(m0+row)*128 + c16*8;
        float4 f0 = *(const float4*)(src);
        float4 f1 = *(const float4*)(src + 4);
        uint4 o;
        o.x = pack2(f0.x, f0.y); o.y = pack2(f0.z, f0.w);
        o.z = pack2(f1.x, f1.y); o.w = pack2(f1.z, f1.w);
        int dst = (row<<8) + ((c16<<4) ^ ((row&7)<<4));
        *(uint4*)(As + dst) = o;
    }

    int lane = tid & 63, w = tid >> 6;
    int wm = w*32;
    int lr = lane & 15, lk = (lane>>4)*8;
    int rb = (lane>>4)*4;

    for (int nt = 0; nt < 5; ++nt) {
        __syncthreads();                       // prev Bs reads done (1st: A staged)
        #pragma unroll
        for (int it = 0; it < 8; ++it) {       // stage B: raw bf16 copy
            int u = it*256 + tid;
            int row = u >> 4, c16 = u & 15;
            int dst = (row<<8) + ((c16<<4) ^ ((row&7)<<4));
            *(uint4*)(Bs + dst) =
                *(const uint4*)(WtB + (size_t)(nt*128+row)*128 + c16*8);
        }
        __syncthreads();

        frag_cd acc[2][8] = {};
        #pragma unroll
        for (int kt = 0; kt < 4; ++kt) {
            int kb2 = (kt*32 + lk)*2;
            frag_ab a0, a1;
            { int r = wm + lr;      a0 = *(const frag_ab*)(As + (r<<8) + (kb2 ^ ((r&7)<<4))); }
            { int r = wm + 16 + lr; a1 = *(const frag_ab*)(As + (r<<8) + (kb2 ^ ((r&7)<<4))); }
            #pragma unroll
            for (int nf = 0; nf < 8; ++nf) {
                int rn = nf*16 + lr;
                frag_ab bf = *(const frag_ab*)(Bs + (rn<<8) + (kb2 ^ ((rn&7)<<4)));
                acc[0][nf] = __builtin_amdgcn_mfma_f32_16x16x32_bf16(a0, bf, acc[0][nf], 0,0,0);
                acc[1][nf] = __builtin_amdgcn_mfma_f32_16x16x32_bf16(a1, bf, acc[1][nf], 0,0,0);
            }
        }

        const float* bsrc = (nt < 2) ? b_in + nt*128
                         : (nt == 2) ? b_lam
                                     : b_gate + (nt-3)*128;
        #pragma unroll
        for (int nf = 0; nf < 8; ++nf) {
            int nl = nf*16 + lr;               // local col within this 128-tile
            float bias = bsrc[nl];
            #pragma unroll
            for (int i = 0; i < 2; ++i)
            #pragma unroll
            for (int r = 0; r < 4; ++r) {
                int m = m0 + wm + i*16 + rb + r;
                float v = acc[i][nf][r] + bias;
                float e = __expf(-v);
                if (nt == 2)      OM[(size_t)m*128 + nl] = f2b(e/(1.f+e));
                else if (nt < 2)  SC[(size_t)m*256 + nt*128 + nl] = f2b(v/(1.f+e));
                else              GATE[(size_t)m*256 + (nt-3)*128 + nl] = f2b(v/(1.f+e));
            }
        }
    }
}

// ---------------- K2: fused fwd+rev complex scans, full-d, bf16 I/O ----------
template<int AXISW, int FIRSTPAIR>
__global__ __launch_bounds__(256) void k_scan2(const u16* __restrict__ SC,
                                               const u16* __restrict__ OM,
                                               const float* __restrict__ trig,
                                               u32* P)
{
    int j = blockIdx.x*256 + threadIdx.x;  // 131072 columns (full d)
    int d = j & 127;
    int col = j >> 7;                      // 0..1023
    int rowbase, stride;
    if (AXISW) { rowbase = (col>>3)*1024 + (col&7); stride = 8; }
    else       { rowbase = col;                     stride = 1024; }

    float cfF = trig[d],     sfF = trig[128+d];
    float cfR = trig[256+d], sfR = trig[384+d];

    long long rowF = rowbase;
    long long rowR = (long long)rowbase + (long long)stride*127;

    float hfr=0.f, hfi=0.f, hrr=0.f, hri=0.f;

    #define SCAN_STEP                                                     \
        u32 uF = *(const u32*)(SC + rowF*256 + 2*d);                      \
        float omF = b2f(OM[rowF*128 + d]);                                \
        u32 uR = *(const u32*)(SC + rowR*256 + 2*d);                      \
        float omR = b2f(OM[rowR*128 + d]);                                \
        float lamF = 1.f - omF, lamR = 1.f - omR;                         \
        float grF = lamF*cfF, giF = lamF*sfF;                             \
        float grR = lamR*cfR, giR = lamR*sfR;                             \
        float ieF = b2f((u16)(uF & 0xffff)), ioF = b2f((u16)(uF >> 16));  \
        float ieR = b2f((u16)(uR & 0xffff)), ioR = b2f((u16)(uR >> 16));  \
        float nfr = fmaf(grF, hfr, fmaf(-giF, hfi, omF*ieF));             \
        float nfi = fmaf(grF, hfi, fmaf( giF, hfr, omF*ioF));             \
        hfr = nfr; hfi = nfi;                                             \
        float nrr = fmaf(grR, hrr, fmaf(-giR, hri, omR*ieR));             \
        float nri = fmaf(grR, hri, fmaf( giR, hrr, omR*ioR));             \
        hrr = nrr; hri = nri;                                             \
        long long piF = rowF*128 + d;                                     \
        long long piR = rowR*128 + d;

    if (FIRSTPAIR) {
        #pragma unroll 4
        for (int t = 0; t < 64; ++t, rowF += stride, rowR -= stride) {
            SCAN_STEP
            P[piF] = pack2(hfr, hfi);
            P[piR] = pack2(hrr, hri);
        }
        #pragma unroll 4
        for (int t = 64; t < 128; ++t, rowF += stride, rowR -= stride) {
            SCAN_STEP
            u32 oF = P[piF];
            P[piF] = pack2(b2f((u16)(oF&0xffff)) + hfr, b2f((u16)(oF>>16)) + hfi);
            u32 oR = P[piR];
            P[piR] = pack2(b2f((u16)(oR&0xffff)) + hrr, b2f((u16)(oR>>16)) + hri);
        }
    } else {
        #pragma unroll 4
        for (int t = 0; t < 128; ++t, rowF += stride, rowR -= stride) {
            SCAN_STEP
            u32 oF = P[piF];
            P[piF] = pack2(b2f((u16)(oF&0xffff)) + hfr, b2f((u16)(oF>>16)) + hfi);
            u32 oR = P[piR];
            P[piR] = pack2(b2f((u16)(oR&0xffff)) + hrr, b2f((u16)(oR>>16)) + hri);
        }
    }
    #undef SCAN_STEP
}

// ---------------- K3: LN + gate + out GEMM; W staged in LDS per 64-k chunk --
#define GETC(v,i) ((i)==0?(v).x:(i)==1?(v).y:(i)==2?(v).z:(v).w)
__global__ __launch_bounds__(256, 3) void k_backend_f32(
    const uint4* __restrict__ P4, const u16* __restrict__ GATE,
    const u16* __restrict__ WoB, const float* __restrict__ ln_w,
    const float* __restrict__ ln_b, const float* __restrict__ bo,
    float* __restrict__ out)
{
    __shared__ u16 fgT[256][68];                // 34 KiB bf16, [channel][row]
    __shared__ u16 wB[64][128];                 // 16 KiB bf16 W chunk [kk][n]
    int tid = threadIdx.x;
    int m0 = blockIdx.x * 64;                   // 2048 blocks
    int r = tid >> 2, q = tid & 3;              // 4 threads per row
    size_t prow4 = (size_t)(m0 + r)*32 + q*8;   // uint4 units (128 u32/row)
    size_t grow = (size_t)(m0 + r)*256;         // u16 units (GATE in ws)

    uint4 ga[4], gb[4];
    #pragma unroll
    for (int g4 = 0; g4 < 4; ++g4) {
        ga[g4] = *(const uint4*)(GATE + grow + q*32 + g4*8);
        gb[g4] = *(const uint4*)(GATE + grow + 128 + q*32 + g4*8);
    }

    uint4 pw[8];                                // 32 packed complex (bf16)
    #pragma unroll
    for (int c4 = 0; c4 < 8; ++c4) pw[c4] = P4[prow4 + c4];

    float fr_[32], fi_[32];
    #pragma unroll
    for (int c4 = 0; c4 < 8; ++c4) {
        #pragma unroll
        for (int w = 0; w < 4; ++w) {
            u32 word = GETC(pw[c4], w);
            int jj = c4*4 + w;
            fr_[jj] = b2f((u16)(word & 0xffff));
            fi_[jj] = b2f((u16)(word >> 16));
        }
    }

    float sum = 0.f, ss = 0.f;
    #pragma unroll
    for (int jj = 0; jj < 32; ++jj) {
        sum += fr_[jj] + fi_[jj];
        ss  += fr_[jj]*fr_[jj] + fi_[jj]*fi_[jj];
    }
    sum += __shfl_xor(sum, 1); sum += __shfl_xor(sum, 2);
    ss  += __shfl_xor(ss, 1);  ss  += __shfl_xor(ss, 2);
    float mu = sum * (1.f/256.f);
    float var = ss * (1.f/256.f) - mu*mu;
    float rstd = rsqrtf(var + 1e-5f);

    #pragma unroll
    for (int jj = 0; jj < 32; ++jj) {
        int pd = q*32 + jj;                     // complex channel 0..127
        int g4 = jj >> 3, e = jj & 7;
        u32 gur = GETC(ga[g4], e>>1), gui = GETC(gb[g4], e>>1);
        float gvr = b2f((u16)((e&1) ? (gur>>16) : (gur&0xffff)));
        float gvi = b2f((u16)((e&1) ? (gui>>16) : (gui&0xffff)));
        float vr = ((fr_[jj] - mu)*rstd*ln_w[pd]     + ln_b[pd])     * gvr;
        float vi = ((fi_[jj] - mu)*rstd*ln_w[128+pd] + ln_b[128+pd]) * gvi;
        fgT[pd][r]     = f2b(vr);
        fgT[128+pd][r] = f2b(vi);
    }

    // out[64][128] = fgT^T @ WoB : 4m x 8n per thread, W LDS-staged per chunk
    int ri = tid >> 4, ci = tid & 15;
    float acc[4][8] = {};
    for (int kc = 0; kc < 4; ++kc) {
        __syncthreads();                        // fgT ready / prev wB reads done
        #pragma unroll
        for (int it = 0; it < 4; ++it) {        // stage 64k x 128n bf16 chunk
            int u = it*256 + tid;               // 1024 uint4 units
            int kk = u >> 4, c8 = u & 15;
            *(uint4*)(&wB[kk][c8*8]) =
                *(const uint4*)(WoB + (size_t)(kc*64 + kk)*128 + c8*8);
        }
        __syncthreads();

        #pragma unroll 4
        for (int kk = 0; kk < 64; ++kk) {
            int k = kc*64 + kk;
            uint2 xr = *(const uint2*)(&fgT[k][ri*4]);
            float xv0 = b2f((u16)(xr.x & 0xffff));
            float xv1 = b2f((u16)(xr.x >> 16));
            float xv2 = b2f((u16)(xr.y & 0xffff));
            float xv3 = b2f((u16)(xr.y >> 16));
            uint4 wv = *(const uint4*)(&wB[kk][ci*8]);
            float w0 = b2f((u16)(wv.x & 0xffff)), w1 = b2f((u16)(wv.x >> 16));
            float w2 = b2f((u16)(wv.y & 0xffff)), w3 = b2f((u16)(wv.y >> 16));
            float w4 = b2f((u16)(wv.z & 0xffff)), w5 = b2f((u16)(wv.z >> 16));
            float w6 = b2f((u16)(wv.w & 0xffff)), w7 = b2f((u16)(wv.w >> 16));
            #define FMA8(i, xv)                                    \
                acc[i][0] = fmaf(xv, w0, acc[i][0]);               \
                acc[i][1] = fmaf(xv, w1, acc[i][1]);               \
                acc[i][2] = fmaf(xv, w2, acc[i][2]);               \
                acc[i][3] = fmaf(xv, w3, acc[i][3]);               \
                acc[i][4] = fmaf(xv, w4, acc[i][4]);               \
                acc[i][5] = fmaf(xv, w5, acc[i][5]);               \
                acc[i][6] = fmaf(xv, w6, acc[i][6]);               \
                acc[i][7] = fmaf(xv, w7, acc[i][7]);
            FMA8(0, xv0) FMA8(1, xv1) FMA8(2, xv2) FMA8(3, xv3)
            #undef FMA8
        }
    }
    #pragma unroll
    for (int i = 0; i < 4; ++i) {
        int m = m0 + ri*4 + i;
        #pragma unroll
        for (int j = 0; j < 8; ++j) {
            int n = ci*8 + j;
            out[(size_t)m*128 + n] = acc[i][j] + bo[n];
        }
    }
}

// ---------------- launch -----------------------------------------------------
extern "C" void kernel_launch(void* const* d_in, const int* in_sizes, int n_in,
                              void* d_out, int out_size, void* d_ws, size_t ws_size,
                              hipStream_t stream)
{
    const float* x      = (const float*)d_in[0];
    const float* W_in   = (const float*)d_in[1];
    const float* b_in   = (const float*)d_in[2];
    const float* W_lam  = (const float*)d_in[3];
    const float* b_lam  = (const float*)d_in[4];
    const float* th_f   = (const float*)d_in[5];
    const float* th_r   = (const float*)d_in[6];
    const float* W_gate = (const float*)d_in[7];
    const float* b_gate = (const float*)d_in[8];
    const float* W_out  = (const float*)d_in[9];
    const float* b_out  = (const float*)d_in[10];
    const float* ln_w   = (const float*)d_in[11];
    const float* ln_b   = (const float*)d_in[12];

    // ws layout: 168,003,584 B <= 168,008,192 B proven-safe envelope
    char* ws = (char*)d_ws;
    u32* P     = (u32*)(ws);                      //  67,108,864 (bf16-pair, full d)
    u16* OM    = (u16*)(ws + 67108864LL);         //  33,554,432 (bf16 om, full d)
    u16* GATE  = (u16*)(ws + 100663296LL);        //  67,108,864 (bf16 gate)
    float* trig= (float*)(ws + 167772160LL);      //   2,048
    u16* WoB   = (u16*)(ws + 167774208LL);        //  65,536 (bf16 W_out)
    u16* WtB   = (u16*)(ws + 167839744LL);        // 163,840 (bf16 front W, n-major)

    // d_out time-shares: SC bf16[M][256] (front->scans) -> out f32[M][128]
    u16* SC   = (u16*)d_out;
    float* out = (float*)d_out;

    hipLaunchKernelGGL(k_prep, dim3(897), dim3(128), 0, stream,
                       th_f, th_r, W_in, W_lam, W_gate, W_out, trig, WoB, WtB);

    hipLaunchKernelGGL(k_front_mfma, dim3(1024), dim3(256), 0, stream,
                       x, WtB, b_in, b_lam, b_gate, SC, OM, GATE);

    hipLaunchKernelGGL(HIP_KERNEL_NAME(k_scan2<0,1>), dim3(512), dim3(256), 0, stream,
                       SC, OM, trig, P);
    hipLaunchKernelGGL(HIP_KERNEL_NAME(k_scan2<1,0>), dim3(512), dim3(256), 0, stream,
                       SC, OM, trig, P);

    hipLaunchKernelGGL(k_backend_f32, dim3(2048), dim3(256), 0, stream,
                       (const uint4*)P, GATE, WoB, ln_w, ln_b, b_out, out);
}

// Round 17
// 411.003 us; speedup vs baseline: 2.2502x; 1.0034x over previous
//
#include <hip/hip_runtime.h>
#include <hip/hip_bf16.h>
#include <math.h>

// Problem constants
#define HH 128
#define WWW 128
#define BB 8
#define MM (HH*WWW*BB)      // 131072 rows (h,w,b)

typedef unsigned int u32;
typedef unsigned short u16;

using frag_ab = __attribute__((ext_vector_type(8))) short;   // 8 bf16
using frag_cd = __attribute__((ext_vector_type(4))) float;   // 4 f32

__device__ __forceinline__ float b2f(u16 s){ return __uint_as_float(((u32)s)<<16); }
__device__ __forceinline__ u16 f2b(float f){
    u32 u = __float_as_uint(f);
    return (u16)((u + 0x7fffu + ((u>>16)&1u)) >> 16);
}
__device__ __forceinline__ u32 pack2(float lo, float hi){
    return (u32)f2b(lo) | ((u32)f2b(hi)<<16);
}

// ---------------- K0: prep: WtB (front weights bf16, n-major), WoB, trig ----
// WtB[n][k], n: 0-255 W_in | 256-383 W_lam | 384-639 W_gate
__global__ __launch_bounds__(128) void k_prep(
    const float* __restrict__ th_f, const float* __restrict__ th_r,
    const float* __restrict__ W_in, const float* __restrict__ W_lam,
    const float* __restrict__ W_gate, const float* __restrict__ W_out,
    float* __restrict__ trig, u16* __restrict__ WoB, u16* __restrict__ WtB)
{
    int t = blockIdx.x*128 + threadIdx.x;     // 897 blocks x 128
    if (t < 81920) {
        int n = t >> 7, k = t & 127;
        float v = (n < 256) ? W_in[k*256 + n]
                : (n < 384) ? W_lam[k*128 + (n-256)]
                            : W_gate[k*256 + (n-384)];
        WtB[t] = f2b(v);
    } else if (t < 114688) {                  // WoB natural order [k][n]
        int u = t - 81920;
        WoB[u] = f2b(W_out[u]);
    } else if (t < 114816) {
        int d = t - 114688;
        trig[d]     = cosf(th_f[d]); trig[128+d] = sinf(th_f[d]);
        trig[256+d] = cosf(th_r[d]); trig[384+d] = sinf(th_r[d]);
    }
}

// ---------------- K0b: cast x f32 -> bf16 (xb aliases P's ws space) ---------
__global__ __launch_bounds__(256) void k_cast(const float4* __restrict__ x,
                                              uint4* __restrict__ xb){
    size_t i = (size_t)blockIdx.x*256 + threadIdx.x;   // 2,097,152 threads
    float4 a = x[2*i], b = x[2*i+1];
    uint4 o;
    o.x = pack2(a.x, a.y); o.y = pack2(a.z, a.w);
    o.z = pack2(b.x, b.y); o.w = pack2(b.z, b.w);
    xb[i] = o;
}

// ---------------- K1: front GEMM via MFMA, nt in grid, 1 barrier ------------
// Grid 5120 = 1024 m-tiles x 5 nt (m-major: bid/5 = mt so sibling blocks share
// the A-tile in L2). nt 0,1 -> SC (silu); nt 2 -> OM (1-sigmoid); 3,4 -> GATE.
__global__ __launch_bounds__(256) void k_front_mfma(
    const u16* __restrict__ xb, const u16* __restrict__ WtB,
    const float* __restrict__ b_in, const float* __restrict__ b_lam,
    const float* __restrict__ b_gate,
    u16* __restrict__ SC, u16* __restrict__ OM, u16* __restrict__ GATE)
{
    __shared__ __align__(16) char As[32768];   // 128 rows x 256B, XOR-swizzled
    __shared__ __align__(16) char Bs[32768];

    int bid = blockIdx.x;
    int mt = bid / 5, nt = bid % 5;
    int m0 = mt * 128;
    int tid = threadIdx.x;

    #pragma unroll
    for (int it = 0; it < 8; ++it) {           // stage A: raw bf16 copy
        int u = it*256 + tid;                  // 2048 16B units
        int row = u >> 4, c16 = u & 15;
        int dst = (row<<8) + ((c16<<4) ^ ((row&7)<<4));
        *(uint4*)(As + dst) =
            *(const uint4*)(xb + (size_t)(m0+row)*128 + c16*8);
    }
    #pragma unroll
    for (int it = 0; it < 8; ++it) {           // stage B: raw bf16 copy
        int u = it*256 + tid;
        int row = u >> 4, c16 = u & 15;
        int dst = (row<<8) + ((c16<<4) ^ ((row&7)<<4));
        *(uint4*)(Bs + dst) =
            *(const uint4*)(WtB + (size_t)(nt*128+row)*128 + c16*8);
    }
    __syncthreads();

    int lane = tid & 63, w = tid >> 6;
    int wm = w*32;
    int lr = lane & 15, lk = (lane>>4)*8;
    int rb = (lane>>4)*4;

    frag_cd acc[2][8] = {};
    #pragma unroll
    for (int kt = 0; kt < 4; ++kt) {
        int kb2 = (kt*32 + lk)*2;
        frag_ab a0, a1;
        { int r = wm + lr;      a0 = *(const frag_ab*)(As + (r<<8) + (kb2 ^ ((r&7)<<4))); }
        { int r = wm + 16 + lr; a1 = *(const frag_ab*)(As + (r<<8) + (kb2 ^ ((r&7)<<4))); }
        #pragma unroll
        for (int nf = 0; nf < 8; ++nf) {
            int rn = nf*16 + lr;
            frag_ab bf = *(const frag_ab*)(Bs + (rn<<8) + (kb2 ^ ((rn&7)<<4)));
            acc[0][nf] = __builtin_amdgcn_mfma_f32_16x16x32_bf16(a0, bf, acc[0][nf], 0,0,0);
            acc[1][nf] = __builtin_amdgcn_mfma_f32_16x16x32_bf16(a1, bf, acc[1][nf], 0,0,0);
        }
    }

    const float* bsrc = (nt < 2) ? b_in + nt*128
                     : (nt == 2) ? b_lam
                                 : b_gate + (nt-3)*128;
    #pragma unroll
    for (int nf = 0; nf < 8; ++nf) {
        int nl = nf*16 + lr;               // local col within this 128-tile
        float bias = bsrc[nl];
        #pragma unroll
        for (int i = 0; i < 2; ++i)
        #pragma unroll
        for (int r = 0; r < 4; ++r) {
            int m = m0 + wm + i*16 + rb + r;
            float v = acc[i][nf][r] + bias;
            float e = __expf(-v);
            float s = __builtin_amdgcn_rcpf(1.f + e);
            if (nt == 2)      OM[(size_t)m*128 + nl] = f2b(e*s);
            else if (nt < 2)  SC[(size_t)m*256 + nt*128 + nl] = f2b(v*s);
            else              GATE[(size_t)m*256 + (nt-3)*128 + nl] = f2b(v*s);
        }
    }
}

// ---------------- K2: fused fwd+rev complex scans, full-d, bf16 I/O ----------
template<int AXISW, int FIRSTPAIR>
__global__ __launch_bounds__(256) void k_scan2(const u16* __restrict__ SC,
                                               const u16* __restrict__ OM,
                                               const float* __restrict__ trig,
                                               u32* P)
{
    int j = blockIdx.x*256 + threadIdx.x;  // 131072 columns (full d)
    int d = j & 127;
    int col = j >> 7;                      // 0..1023
    int rowbase, stride;
    if (AXISW) { rowbase = (col>>3)*1024 + (col&7); stride = 8; }
    else       { rowbase = col;                     stride = 1024; }

    float cfF = trig[d],     sfF = trig[128+d];
    float cfR = trig[256+d], sfR = trig[384+d];

    long long rowF = rowbase;
    long long rowR = (long long)rowbase + (long long)stride*127;

    float hfr=0.f, hfi=0.f, hrr=0.f, hri=0.f;

    #define SCAN_STEP                                                     \
        u32 uF = *(const u32*)(SC + rowF*256 + 2*d);                      \
        float omF = b2f(OM[rowF*128 + d]);                                \
        u32 uR = *(const u32*)(SC + rowR*256 + 2*d);                      \
        float omR = b2f(OM[rowR*128 + d]);                                \
        float lamF = 1.f - omF, lamR = 1.f - omR;                         \
        float grF = lamF*cfF, giF = lamF*sfF;                             \
        float grR = lamR*cfR, giR = lamR*sfR;                             \
        float ieF = b2f((u16)(uF & 0xffff)), ioF = b2f((u16)(uF >> 16));  \
        float ieR = b2f((u16)(uR & 0xffff)), ioR = b2f((u16)(uR >> 16));  \
        float nfr = fmaf(grF, hfr, fmaf(-giF, hfi, omF*ieF));             \
        float nfi = fmaf(grF, hfi, fmaf( giF, hfr, omF*ioF));             \
        hfr = nfr; hfi = nfi;                                             \
        float nrr = fmaf(grR, hrr, fmaf(-giR, hri, omR*ieR));             \
        float nri = fmaf(grR, hri, fmaf( giR, hrr, omR*ioR));             \
        hrr = nrr; hri = nri;                                             \
        long long piF = rowF*128 + d;                                     \
        long long piR = rowR*128 + d;

    if (FIRSTPAIR) {
        #pragma unroll 4
        for (int t = 0; t < 64; ++t, rowF += stride, rowR -= stride) {
            SCAN_STEP
            P[piF] = pack2(hfr, hfi);
            P[piR] = pack2(hrr, hri);
        }
        #pragma unroll 4
        for (int t = 64; t < 128; ++t, rowF += stride, rowR -= stride) {
            SCAN_STEP
            u32 oF = P[piF];
            P[piF] = pack2(b2f((u16)(oF&0xffff)) + hfr, b2f((u16)(oF>>16)) + hfi);
            u32 oR = P[piR];
            P[piR] = pack2(b2f((u16)(oR&0xffff)) + hrr, b2f((u16)(oR>>16)) + hri);
        }
    } else {
        #pragma unroll 4
        for (int t = 0; t < 128; ++t, rowF += stride, rowR -= stride) {
            SCAN_STEP
            u32 oF = P[piF];
            P[piF] = pack2(b2f((u16)(oF&0xffff)) + hfr, b2f((u16)(oF>>16)) + hfi);
            u32 oR = P[piR];
            P[piR] = pack2(b2f((u16)(oR&0xffff)) + hrr, b2f((u16)(oR>>16)) + hri);
        }
    }
    #undef SCAN_STEP
}

// ---------------- K3: LN + gate + out GEMM; W staged in LDS per 64-k chunk --
#define GETC(v,i) ((i)==0?(v).x:(i)==1?(v).y:(i)==2?(v).z:(v).w)
__global__ __launch_bounds__(256, 3) void k_backend_f32(
    const uint4* __restrict__ P4, const u16* __restrict__ GATE,
    const u16* __restrict__ WoB, const float* __restrict__ ln_w,
    const float* __restrict__ ln_b, const float* __restrict__ bo,
    float* __restrict__ out)
{
    __shared__ u16 fgT[256][68];                // 34 KiB bf16, [channel][row]
    __shared__ u16 wB[64][128];                 // 16 KiB bf16 W chunk [kk][n]
    int tid = threadIdx.x;
    int m0 = blockIdx.x * 64;                   // 2048 blocks
    int r = tid >> 2, q = tid & 3;              // 4 threads per row
    size_t prow4 = (size_t)(m0 + r)*32 + q*8;   // uint4 units (128 u32/row)
    size_t grow = (size_t)(m0 + r)*256;         // u16 units (GATE in ws)

    uint4 ga[4], gb[4];
    #pragma unroll
    for (int g4 = 0; g4 < 4; ++g4) {
        ga[g4] = *(const uint4*)(GATE + grow + q*32 + g4*8);
        gb[g4] = *(const uint4*)(GATE + grow + 128 + q*32 + g4*8);
    }

    uint4 pw[8];                                // 32 packed complex (bf16)
    #pragma unroll
    for (int c4 = 0; c4 < 8; ++c4) pw[c4] = P4[prow4 + c4];

    float fr_[32], fi_[32];
    #pragma unroll
    for (int c4 = 0; c4 < 8; ++c4) {
        #pragma unroll
        for (int w = 0; w < 4; ++w) {
            u32 word = GETC(pw[c4], w);
            int jj = c4*4 + w;
            fr_[jj] = b2f((u16)(word & 0xffff));
            fi_[jj] = b2f((u16)(word >> 16));
        }
    }

    float sum = 0.f, ss = 0.f;
    #pragma unroll
    for (int jj = 0; jj < 32; ++jj) {
        sum += fr_[jj] + fi_[jj];
        ss  += fr_[jj]*fr_[jj] + fi_[jj]*fi_[jj];
    }
    sum += __shfl_xor(sum, 1); sum += __shfl_xor(sum, 2);
    ss  += __shfl_xor(ss, 1);  ss  += __shfl_xor(ss, 2);
    float mu = sum * (1.f/256.f);
    float var = ss * (1.f/256.f) - mu*mu;
    float rstd = rsqrtf(var + 1e-5f);

    #pragma unroll
    for (int jj = 0; jj < 32; ++jj) {
        int pd = q*32 + jj;                     // complex channel 0..127
        int g4 = jj >> 3, e = jj & 7;
        u32 gur = GETC(ga[g4], e>>1), gui = GETC(gb[g4], e>>1);
        float gvr = b2f((u16)((e&1) ? (gur>>16) : (gur&0xffff)));
        float gvi = b2f((u16)((e&1) ? (gui>>16) : (gui&0xffff)));
        float vr = ((fr_[jj] - mu)*rstd*ln_w[pd]     + ln_b[pd])     * gvr;
        float vi = ((fi_[jj] - mu)*rstd*ln_w[128+pd] + ln_b[128+pd]) * gvi;
        fgT[pd][r]     = f2b(vr);
        fgT[128+pd][r] = f2b(vi);
    }

    // out[64][128] = fgT^T @ WoB : 4m x 8n per thread, W LDS-staged per chunk
    int ri = tid >> 4, ci = tid & 15;
    float acc[4][8] = {};
    for (int kc = 0; kc < 4; ++kc) {
        __syncthreads();                        // fgT ready / prev wB reads done
        #pragma unroll
        for (int it = 0; it < 4; ++it) {        // stage 64k x 128n bf16 chunk
            int u = it*256 + tid;               // 1024 uint4 units
            int kk = u >> 4, c8 = u & 15;
            *(uint4*)(&wB[kk][c8*8]) =
                *(const uint4*)(WoB + (size_t)(kc*64 + kk)*128 + c8*8);
        }
        __syncthreads();

        #pragma unroll 4
        for (int kk = 0; kk < 64; ++kk) {
            int k = kc*64 + kk;
            uint2 xr = *(const uint2*)(&fgT[k][ri*4]);
            float xv0 = b2f((u16)(xr.x & 0xffff));
            float xv1 = b2f((u16)(xr.x >> 16));
            float xv2 = b2f((u16)(xr.y & 0xffff));
            float xv3 = b2f((u16)(xr.y >> 16));
            uint4 wv = *(const uint4*)(&wB[kk][ci*8]);
            float w0 = b2f((u16)(wv.x & 0xffff)), w1 = b2f((u16)(wv.x >> 16));
            float w2 = b2f((u16)(wv.y & 0xffff)), w3 = b2f((u16)(wv.y >> 16));
            float w4 = b2f((u16)(wv.z & 0xffff)), w5 = b2f((u16)(wv.z >> 16));
            float w6 = b2f((u16)(wv.w & 0xffff)), w7 = b2f((u16)(wv.w >> 16));
            #define FMA8(i, xv)                                    \
                acc[i][0] = fmaf(xv, w0, acc[i][0]);               \
                acc[i][1] = fmaf(xv, w1, acc[i][1]);               \
                acc[i][2] = fmaf(xv, w2, acc[i][2]);               \
                acc[i][3] = fmaf(xv, w3, acc[i][3]);               \
                acc[i][4] = fmaf(xv, w4, acc[i][4]);               \
                acc[i][5] = fmaf(xv, w5, acc[i][5]);               \
                acc[i][6] = fmaf(xv, w6, acc[i][6]);               \
                acc[i][7] = fmaf(xv, w7, acc[i][7]);
            FMA8(0, xv0) FMA8(1, xv1) FMA8(2, xv2) FMA8(3, xv3)
            #undef FMA8
        }
    }
    #pragma unroll
    for (int i = 0; i < 4; ++i) {
        int m = m0 + ri*4 + i;
        #pragma unroll
        for (int j = 0; j < 8; ++j) {
            int n = ci*8 + j;
            out[(size_t)m*128 + n] = acc[i][j] + bo[n];
        }
    }
}

// ---------------- launch -----------------------------------------------------
extern "C" void kernel_launch(void* const* d_in, const int* in_sizes, int n_in,
                              void* d_out, int out_size, void* d_ws, size_t ws_size,
                              hipStream_t stream)
{
    const float* x      = (const float*)d_in[0];
    const float* W_in   = (const float*)d_in[1];
    const float* b_in   = (const float*)d_in[2];
    const float* W_lam  = (const float*)d_in[3];
    const float* b_lam  = (const float*)d_in[4];
    const float* th_f   = (const float*)d_in[5];
    const float* th_r   = (const float*)d_in[6];
    const float* W_gate = (const float*)d_in[7];
    const float* b_gate = (const float*)d_in[8];
    const float* W_out  = (const float*)d_in[9];
    const float* b_out  = (const float*)d_in[10];
    const float* ln_w   = (const float*)d_in[11];
    const float* ln_b   = (const float*)d_in[12];

    // ws layout: 168,003,584 B <= 168,008,192 B proven-safe envelope
    char* ws = (char*)d_ws;
    u32* P     = (u32*)(ws);                      //  67,108,864 (bf16-pair, full d)
    u16* xb    = (u16*)(ws);                      //  33,554,432 ALIASES P (disjoint
                                                  //  lifetime: xb dies at front end;
                                                  //  P first written by scan1)
    u16* OM    = (u16*)(ws + 67108864LL);         //  33,554,432 (bf16 om, full d)
    u16* GATE  = (u16*)(ws + 100663296LL);        //  67,108,864 (bf16 gate)
    float* trig= (float*)(ws + 167772160LL);      //   2,048
    u16* WoB   = (u16*)(ws + 167774208LL);        //  65,536 (bf16 W_out)
    u16* WtB   = (u16*)(ws + 167839744LL);        // 163,840 (bf16 front W, n-major)

    // d_out time-shares: SC bf16[M][256] (front->scans) -> out f32[M][128]
    u16* SC   = (u16*)d_out;
    float* out = (float*)d_out;

    hipLaunchKernelGGL(k_prep, dim3(897), dim3(128), 0, stream,
                       th_f, th_r, W_in, W_lam, W_gate, W_out, trig, WoB, WtB);
    hipLaunchKernelGGL(k_cast, dim3(8192), dim3(256), 0, stream,
                       (const float4*)x, (uint4*)xb);

    hipLaunchKernelGGL(k_front_mfma, dim3(5120), dim3(256), 0, stream,
                       xb, WtB, b_in, b_lam, b_gate, SC, OM, GATE);

    hipLaunchKernelGGL(HIP_KERNEL_NAME(k_scan2<0,1>), dim3(512), dim3(256), 0, stream,
                       SC, OM, trig, P);
    hipLaunchKernelGGL(HIP_KERNEL_NAME(k_scan2<1,0>), dim3(512), dim3(256), 0, stream,
                       SC, OM, trig, P);

    hipLaunchKernelGGL(k_backend_f32, dim3(2048), dim3(256), 0, stream,
                       (const uint4*)P, GATE, WoB, ln_w, ln_b, b_out, out);
}

// Round 18
// 336.332 us; speedup vs baseline: 2.7498x; 1.2220x over previous
//
#include <hip/hip_runtime.h>
#include <hip/hip_bf16.h>
#include <math.h>

// Problem constants
#define HH 128
#define WWW 128
#define BB 8
#define MM (HH*WWW*BB)      // 131072 rows (h,w,b)

typedef unsigned int u32;
typedef unsigned short u16;

using frag_ab = __attribute__((ext_vector_type(8))) short;   // 8 bf16
using frag_cd = __attribute__((ext_vector_type(4))) float;   // 4 f32

__device__ __forceinline__ float b2f(u16 s){ return __uint_as_float(((u32)s)<<16); }
__device__ __forceinline__ u16 f2b(float f){
    u32 u = __float_as_uint(f);
    return (u16)((u + 0x7fffu + ((u>>16)&1u)) >> 16);
}
__device__ __forceinline__ u32 pack2(float lo, float hi){
    return (u32)f2b(lo) | ((u32)f2b(hi)<<16);
}

// ---------------- K0: prep: WtB (front W bf16 n-major), WoTn, trig ----------
// WtB[n][k], n: 0-255 W_in | 256-383 W_lam | 384-639 W_gate
// WoTn[n][k] = W_out[k][n]  (n<128, k<256; no channel permutation)
__global__ __launch_bounds__(128) void k_prep(
    const float* __restrict__ th_f, const float* __restrict__ th_r,
    const float* __restrict__ W_in, const float* __restrict__ W_lam,
    const float* __restrict__ W_gate, const float* __restrict__ W_out,
    float* __restrict__ trig, u16* __restrict__ WoTn, u16* __restrict__ WtB)
{
    int t = blockIdx.x*128 + threadIdx.x;     // 897 blocks x 128
    if (t < 81920) {
        int n = t >> 7, k = t & 127;
        float v = (n < 256) ? W_in[k*256 + n]
                : (n < 384) ? W_lam[k*128 + (n-256)]
                            : W_gate[k*256 + (n-384)];
        WtB[t] = f2b(v);
    } else if (t < 114688) {                  // WoTn[n][k] = W_out[k][n]
        int u = t - 81920;
        int n = u >> 8, k = u & 255;
        WoTn[u] = f2b(W_out[(size_t)k*128 + n]);
    } else if (t < 114816) {
        int d = t - 114688;
        trig[d]     = cosf(th_f[d]); trig[128+d] = sinf(th_f[d]);
        trig[256+d] = cosf(th_r[d]); trig[384+d] = sinf(th_r[d]);
    }
}

// ---------------- K0b: cast x f32 -> bf16 (xb aliases P's ws space) ---------
__global__ __launch_bounds__(256) void k_cast(const float4* __restrict__ x,
                                              uint4* __restrict__ xb){
    size_t i = (size_t)blockIdx.x*256 + threadIdx.x;   // 2,097,152 threads
    float4 a = x[2*i], b = x[2*i+1];
    uint4 o;
    o.x = pack2(a.x, a.y); o.y = pack2(a.z, a.w);
    o.z = pack2(b.x, b.y); o.w = pack2(b.z, b.w);
    xb[i] = o;
}

// ---------------- K1: front GEMM via MFMA, nt in grid, 1 barrier ------------
__global__ __launch_bounds__(256) void k_front_mfma(
    const u16* __restrict__ xb, const u16* __restrict__ WtB,
    const float* __restrict__ b_in, const float* __restrict__ b_lam,
    const float* __restrict__ b_gate,
    u16* __restrict__ SC, u16* __restrict__ OM, u16* __restrict__ GATE)
{
    __shared__ __align__(16) char As[32768];   // 128 rows x 256B, XOR-swizzled
    __shared__ __align__(16) char Bs[32768];

    int bid = blockIdx.x;
    int mt = bid / 5, nt = bid % 5;
    int m0 = mt * 128;
    int tid = threadIdx.x;

    #pragma unroll
    for (int it = 0; it < 8; ++it) {           // stage A: raw bf16 copy
        int u = it*256 + tid;
        int row = u >> 4, c16 = u & 15;
        int dst = (row<<8) + ((c16<<4) ^ ((row&7)<<4));
        *(uint4*)(As + dst) =
            *(const uint4*)(xb + (size_t)(m0+row)*128 + c16*8);
    }
    #pragma unroll
    for (int it = 0; it < 8; ++it) {           // stage B: raw bf16 copy
        int u = it*256 + tid;
        int row = u >> 4, c16 = u & 15;
        int dst = (row<<8) + ((c16<<4) ^ ((row&7)<<4));
        *(uint4*)(Bs + dst) =
            *(const uint4*)(WtB + (size_t)(nt*128+row)*128 + c16*8);
    }
    __syncthreads();

    int lane = tid & 63, w = tid >> 6;
    int wm = w*32;
    int lr = lane & 15, lk = (lane>>4)*8;
    int rb = (lane>>4)*4;

    frag_cd acc[2][8] = {};
    #pragma unroll
    for (int kt = 0; kt < 4; ++kt) {
        int kb2 = (kt*32 + lk)*2;
        frag_ab a0, a1;
        { int r = wm + lr;      a0 = *(const frag_ab*)(As + (r<<8) + (kb2 ^ ((r&7)<<4))); }
        { int r = wm + 16 + lr; a1 = *(const frag_ab*)(As + (r<<8) + (kb2 ^ ((r&7)<<4))); }
        #pragma unroll
        for (int nf = 0; nf < 8; ++nf) {
            int rn = nf*16 + lr;
            frag_ab bf = *(const frag_ab*)(Bs + (rn<<8) + (kb2 ^ ((rn&7)<<4)));
            acc[0][nf] = __builtin_amdgcn_mfma_f32_16x16x32_bf16(a0, bf, acc[0][nf], 0,0,0);
            acc[1][nf] = __builtin_amdgcn_mfma_f32_16x16x32_bf16(a1, bf, acc[1][nf], 0,0,0);
        }
    }

    const float* bsrc = (nt < 2) ? b_in + nt*128
                     : (nt == 2) ? b_lam
                                 : b_gate + (nt-3)*128;
    #pragma unroll
    for (int nf = 0; nf < 8; ++nf) {
        int nl = nf*16 + lr;
        float bias = bsrc[nl];
        #pragma unroll
        for (int i = 0; i < 2; ++i)
        #pragma unroll
        for (int r = 0; r < 4; ++r) {
            int m = m0 + wm + i*16 + rb + r;
            float v = acc[i][nf][r] + bias;
            float e = __expf(-v);
            float s = __builtin_amdgcn_rcpf(1.f + e);
            if (nt == 2)      OM[(size_t)m*128 + nl] = f2b(e*s);
            else if (nt < 2)  SC[(size_t)m*256 + nt*128 + nl] = f2b(v*s);
            else              GATE[(size_t)m*256 + (nt-3)*128 + nl] = f2b(v*s);
        }
    }
}

// ---------------- K2: fused fwd+rev complex scans, full-d, bf16 I/O ----------
template<int AXISW, int FIRSTPAIR>
__global__ __launch_bounds__(256) void k_scan2(const u16* __restrict__ SC,
                                               const u16* __restrict__ OM,
                                               const float* __restrict__ trig,
                                               u32* P)
{
    int j = blockIdx.x*256 + threadIdx.x;  // 131072 columns (full d)
    int d = j & 127;
    int col = j >> 7;                      // 0..1023
    int rowbase, stride;
    if (AXISW) { rowbase = (col>>3)*1024 + (col&7); stride = 8; }
    else       { rowbase = col;                     stride = 1024; }

    float cfF = trig[d],     sfF = trig[128+d];
    float cfR = trig[256+d], sfR = trig[384+d];

    long long rowF = rowbase;
    long long rowR = (long long)rowbase + (long long)stride*127;

    float hfr=0.f, hfi=0.f, hrr=0.f, hri=0.f;

    #define SCAN_STEP                                                     \
        u32 uF = *(const u32*)(SC + rowF*256 + 2*d);                      \
        float omF = b2f(OM[rowF*128 + d]);                                \
        u32 uR = *(const u32*)(SC + rowR*256 + 2*d);                      \
        float omR = b2f(OM[rowR*128 + d]);                                \
        float lamF = 1.f - omF, lamR = 1.f - omR;                         \
        float grF = lamF*cfF, giF = lamF*sfF;                             \
        float grR = lamR*cfR, giR = lamR*sfR;                             \
        float ieF = b2f((u16)(uF & 0xffff)), ioF = b2f((u16)(uF >> 16));  \
        float ieR = b2f((u16)(uR & 0xffff)), ioR = b2f((u16)(uR >> 16));  \
        float nfr = fmaf(grF, hfr, fmaf(-giF, hfi, omF*ieF));             \
        float nfi = fmaf(grF, hfi, fmaf( giF, hfr, omF*ioF));             \
        hfr = nfr; hfi = nfi;                                             \
        float nrr = fmaf(grR, hrr, fmaf(-giR, hri, omR*ieR));             \
        float nri = fmaf(grR, hri, fmaf( giR, hrr, omR*ioR));             \
        hrr = nrr; hri = nri;                                             \
        long long piF = rowF*128 + d;                                     \
        long long piR = rowR*128 + d;

    if (FIRSTPAIR) {
        #pragma unroll 4
        for (int t = 0; t < 64; ++t, rowF += stride, rowR -= stride) {
            SCAN_STEP
            P[piF] = pack2(hfr, hfi);
            P[piR] = pack2(hrr, hri);
        }
        #pragma unroll 4
        for (int t = 64; t < 128; ++t, rowF += stride, rowR -= stride) {
            SCAN_STEP
            u32 oF = P[piF];
            P[piF] = pack2(b2f((u16)(oF&0xffff)) + hfr, b2f((u16)(oF>>16)) + hfi);
            u32 oR = P[piR];
            P[piR] = pack2(b2f((u16)(oR&0xffff)) + hrr, b2f((u16)(oR>>16)) + hri);
        }
    } else {
        #pragma unroll 4
        for (int t = 0; t < 128; ++t, rowF += stride, rowR -= stride) {
            SCAN_STEP
            u32 oF = P[piF];
            P[piF] = pack2(b2f((u16)(oF&0xffff)) + hfr, b2f((u16)(oF>>16)) + hfi);
            u32 oR = P[piR];
            P[piR] = pack2(b2f((u16)(oR&0xffff)) + hrr, b2f((u16)(oR>>16)) + hri);
        }
    }
    #undef SCAN_STEP
}

// ---------------- K3: LN + gate + out GEMM via MFMA -------------------------
// LN/gate math unchanged (proven); fg stored natural [m][k] in LDS; B = WoTn
// rows staged per 64-k chunk with 16B XOR swizzle; r16-proven MFMA recipe.
#define GETC(v,i) ((i)==0?(v).x:(i)==1?(v).y:(i)==2?(v).z:(v).w)
__global__ __launch_bounds__(256) void k_backend_mfma(
    const uint4* __restrict__ P4, const u16* __restrict__ GATE,
    const u16* __restrict__ WoTn, const float* __restrict__ ln_w,
    const float* __restrict__ ln_b, const float* __restrict__ bo,
    float* __restrict__ out)
{
    __shared__ u16 fgM[64][264];                // 33.8 KiB bf16, [m][k], +8 pad
    __shared__ __align__(16) char wBs[16384];   // 16 KiB: B chunk [n][64k] swz
    int tid = threadIdx.x;
    int m0 = blockIdx.x * 64;                   // 2048 blocks
    int r = tid >> 2, q = tid & 3;              // 4 threads per row
    size_t prow4 = (size_t)(m0 + r)*32 + q*8;   // uint4 units (128 u32/row)
    size_t grow = (size_t)(m0 + r)*256;         // u16 units (GATE in ws)

    uint4 ga[4], gb[4];
    #pragma unroll
    for (int g4 = 0; g4 < 4; ++g4) {
        ga[g4] = *(const uint4*)(GATE + grow + q*32 + g4*8);
        gb[g4] = *(const uint4*)(GATE + grow + 128 + q*32 + g4*8);
    }

    uint4 pw[8];                                // 32 packed complex (bf16)
    #pragma unroll
    for (int c4 = 0; c4 < 8; ++c4) pw[c4] = P4[prow4 + c4];

    float fr_[32], fi_[32];
    #pragma unroll
    for (int c4 = 0; c4 < 8; ++c4) {
        #pragma unroll
        for (int w = 0; w < 4; ++w) {
            u32 word = GETC(pw[c4], w);
            int jj = c4*4 + w;
            fr_[jj] = b2f((u16)(word & 0xffff));
            fi_[jj] = b2f((u16)(word >> 16));
        }
    }

    float sum = 0.f, ss = 0.f;
    #pragma unroll
    for (int jj = 0; jj < 32; ++jj) {
        sum += fr_[jj] + fi_[jj];
        ss  += fr_[jj]*fr_[jj] + fi_[jj]*fi_[jj];
    }
    sum += __shfl_xor(sum, 1); sum += __shfl_xor(sum, 2);
    ss  += __shfl_xor(ss, 1);  ss  += __shfl_xor(ss, 2);
    float mu = sum * (1.f/256.f);
    float var = ss * (1.f/256.f) - mu*mu;
    float rstd = rsqrtf(var + 1e-5f);

    #pragma unroll
    for (int jj = 0; jj < 32; ++jj) {
        int pd = q*32 + jj;                     // complex channel 0..127
        int g4 = jj >> 3, e = jj & 7;
        u32 gur = GETC(ga[g4], e>>1), gui = GETC(gb[g4], e>>1);
        float gvr = b2f((u16)((e&1) ? (gur>>16) : (gur&0xffff)));
        float gvi = b2f((u16)((e&1) ? (gui>>16) : (gui&0xffff)));
        float vr = ((fr_[jj] - mu)*rstd*ln_w[pd]     + ln_b[pd])     * gvr;
        float vi = ((fi_[jj] - mu)*rstd*ln_w[128+pd] + ln_b[128+pd]) * gvi;
        fgM[r][pd]       = f2b(vr);             // feature k = pd (real)
        fgM[r][128 + pd] = f2b(vi);             // feature k = 128+pd (imag)
    }

    // out[64][128] = fgM @ WoTn^T via MFMA; wave w owns rows w*16..w*16+15
    int lane = tid & 63, w = tid >> 6;
    int lr = lane & 15, lk = (lane>>4)*8;
    int rb = (lane>>4)*4;

    frag_cd acc[8] = {};
    for (int kc = 0; kc < 4; ++kc) {
        __syncthreads();                        // fgM ready / prev wBs reads done
        #pragma unroll
        for (int it = 0; it < 4; ++it) {        // stage B chunk: 128n x 64k bf16
            int u = it*256 + tid;               // 1024 uint4 units
            int n = u >> 3, c8 = u & 7;
            int dst = (n<<7) + ((c8<<4) ^ ((n&7)<<4));
            *(uint4*)(wBs + dst) =
                *(const uint4*)(WoTn + (size_t)n*256 + kc*64 + c8*8);
        }
        __syncthreads();

        #pragma unroll
        for (int ks = 0; ks < 2; ++ks) {
            int kglob = kc*64 + ks*32 + lk;
            frag_ab a = *(const frag_ab*)(&fgM[w*16 + lr][kglob]);
            int kb2 = (ks*32 + lk)*2;           // byte offset in 128B row
            #pragma unroll
            for (int nf = 0; nf < 8; ++nf) {
                int rn = nf*16 + lr;
                frag_ab b = *(const frag_ab*)(wBs + (rn<<7) + (kb2 ^ ((rn&7)<<4)));
                acc[nf] = __builtin_amdgcn_mfma_f32_16x16x32_bf16(a, b, acc[nf], 0,0,0);
            }
        }
    }

    #pragma unroll
    for (int nf = 0; nf < 8; ++nf) {
        int n = nf*16 + lr;
        float bias = bo[n];
        #pragma unroll
        for (int rr = 0; rr < 4; ++rr) {
            int m = m0 + w*16 + rb + rr;
            out[(size_t)m*128 + n] = acc[nf][rr] + bias;
        }
    }
}

// ---------------- launch -----------------------------------------------------
extern "C" void kernel_launch(void* const* d_in, const int* in_sizes, int n_in,
                              void* d_out, int out_size, void* d_ws, size_t ws_size,
                              hipStream_t stream)
{
    const float* x      = (const float*)d_in[0];
    const float* W_in   = (const float*)d_in[1];
    const float* b_in   = (const float*)d_in[2];
    const float* W_lam  = (const float*)d_in[3];
    const float* b_lam  = (const float*)d_in[4];
    const float* th_f   = (const float*)d_in[5];
    const float* th_r   = (const float*)d_in[6];
    const float* W_gate = (const float*)d_in[7];
    const float* b_gate = (const float*)d_in[8];
    const float* W_out  = (const float*)d_in[9];
    const float* b_out  = (const float*)d_in[10];
    const float* ln_w   = (const float*)d_in[11];
    const float* ln_b   = (const float*)d_in[12];

    // ws layout: 168,003,584 B <= 168,008,192 B proven-safe envelope
    char* ws = (char*)d_ws;
    u32* P     = (u32*)(ws);                      //  67,108,864 (bf16-pair, full d)
    u16* xb    = (u16*)(ws);                      //  33,554,432 ALIASES P (disjoint
                                                  //  lifetime: xb dies at front end;
                                                  //  P first written by scan1)
    u16* OM    = (u16*)(ws + 67108864LL);         //  33,554,432 (bf16 om, full d)
    u16* GATE  = (u16*)(ws + 100663296LL);        //  67,108,864 (bf16 gate)
    float* trig= (float*)(ws + 167772160LL);      //   2,048
    u16* WoTn  = (u16*)(ws + 167774208LL);        //  65,536 (bf16 W_out, n-major)
    u16* WtB   = (u16*)(ws + 167839744LL);        // 163,840 (bf16 front W, n-major)

    // d_out time-shares: SC bf16[M][256] (front->scans) -> out f32[M][128]
    u16* SC   = (u16*)d_out;
    float* out = (float*)d_out;

    hipLaunchKernelGGL(k_prep, dim3(897), dim3(128), 0, stream,
                       th_f, th_r, W_in, W_lam, W_gate, W_out, trig, WoTn, WtB);
    hipLaunchKernelGGL(k_cast, dim3(8192), dim3(256), 0, stream,
                       (const float4*)x, (uint4*)xb);

    hipLaunchKernelGGL(k_front_mfma, dim3(5120), dim3(256), 0, stream,
                       xb, WtB, b_in, b_lam, b_gate, SC, OM, GATE);

    hipLaunchKernelGGL(HIP_KERNEL_NAME(k_scan2<0,1>), dim3(512), dim3(256), 0, stream,
                       SC, OM, trig, P);
    hipLaunchKernelGGL(HIP_KERNEL_NAME(k_scan2<1,0>), dim3(512), dim3(256), 0, stream,
                       SC, OM, trig, P);

    hipLaunchKernelGGL(k_backend_mfma, dim3(2048), dim3(256), 0, stream,
                       (const uint4*)P, GATE, WoTn, ln_w, ln_b, b_out, out);
}